// Round 1
// baseline (1502.572 us; speedup 1.0000x reference)
//
#include <hip/hip_runtime.h>

#define BB 64
#define CC 96
#define HH 56
#define WW 56
#define HWSZ (HH*WW)          // 3136
#define CHW (CC*HWSZ)         // 301056
#define NTOT ((size_t)BB*CHW) // 19267584
#define S_SPLIT 32
#define CHUNK (CHW/S_SPLIT)   // 9408
#define HD 384

__device__ __forceinline__ float gelu_f(float x) {
    return 0.5f*x*(1.0f + erff(x*0.70710678118654752f));
}

// ---------------- GroupNorm(1,C) stats: two-stage deterministic reduction ----------------
__global__ __launch_bounds__(256) void gn_partial(const float* __restrict__ in, float2* __restrict__ part) {
    int b = blockIdx.y, s = blockIdx.x;
    const float* p = in + (size_t)b*CHW + (size_t)s*CHUNK;
    float sum = 0.f, sq = 0.f;
    for (int i = threadIdx.x; i < CHUNK; i += 256) {
        float v = p[i];
        sum += v; sq += v*v;
    }
    for (int off = 32; off > 0; off >>= 1) {
        sum += __shfl_down(sum, off);
        sq  += __shfl_down(sq,  off);
    }
    __shared__ float2 red[4];
    int wid = threadIdx.x >> 6, lane = threadIdx.x & 63;
    if (lane == 0) red[wid] = make_float2(sum, sq);
    __syncthreads();
    if (threadIdx.x == 0) {
        for (int i = 1; i < 4; i++) { sum += red[i].x; sq += red[i].y; }
        part[b*S_SPLIT + s] = make_float2(sum, sq);
    }
}

__global__ void gn_final(const float2* __restrict__ part, float2* __restrict__ stats) {
    int b = threadIdx.x;
    if (b >= BB) return;
    float s = 0.f, q = 0.f;
    for (int i = 0; i < S_SPLIT; i++) { float2 v = part[b*S_SPLIT + i]; s += v.x; q += v.y; }
    float mean = s / (float)CHW;
    float var  = q / (float)CHW - mean*mean;
    float rstd = rsqrtf(var + 1e-5f);
    stats[b] = make_float2(mean, rstd);
}

// ---------------- normalize (+optional gelu), in place, float4 ----------------
template<bool G>
__global__ __launch_bounds__(256) void gn_apply(float* __restrict__ t, const float2* __restrict__ stats,
                                                const float* __restrict__ gam, const float* __restrict__ bet) {
    int i = blockIdx.x*256 + threadIdx.x;        // over NTOT/4
    int b = i / (CHW/4);
    int c = (i / (HWSZ/4)) % CC;
    float2 st = stats[b];
    float g  = gam[c]*st.y;
    float bb = bet[c] - st.x*g;
    float4 v = reinterpret_cast<float4*>(t)[i];
    v.x = v.x*g + bb; v.y = v.y*g + bb; v.z = v.z*g + bb; v.w = v.w*g + bb;
    if (G) { v.x = gelu_f(v.x); v.y = gelu_f(v.y); v.z = gelu_f(v.z); v.w = gelu_f(v.w); }
    reinterpret_cast<float4*>(t)[i] = v;
}

// ---------------- 1x1 conv (per-batch GEMM 96x96 x 96x3136), optional pre-norm of input, optional residual ----------------
template<bool PRE_NORM, bool ADD_RES>
__global__ __launch_bounds__(256) void conv96(const float* __restrict__ in,
        const float* __restrict__ wgt, const float* __restrict__ bias,
        const float2* __restrict__ stats, const float* __restrict__ gam, const float* __restrict__ bet,
        const float* __restrict__ res, float* __restrict__ out) {
    __shared__ float xs[CC][64];
    int b = blockIdx.y;
    int hw0 = blockIdx.x * 64;
    const float* ip = in + (size_t)b*CHW + hw0;
    float mean = 0.f, rstd = 1.f;
    if (PRE_NORM) { float2 st = stats[b]; mean = st.x; rstd = st.y; }
    for (int i = threadIdx.x; i < CC*64; i += 256) {
        int c = i >> 6, col = i & 63;
        float v = ip[c*HWSZ + col];
        if (PRE_NORM) v = (v - mean)*rstd*gam[c] + bet[c];
        xs[c][col] = v;
    }
    __syncthreads();
    int col = threadIdx.x & 63;
    int og = __builtin_amdgcn_readfirstlane((int)(threadIdx.x >> 6));
    const float* wp = wgt + og*24*CC;
    float acc[24];
    #pragma unroll
    for (int k = 0; k < 24; k++) acc[k] = 0.f;
    #pragma unroll 4
    for (int c = 0; c < CC; c++) {
        float xv = xs[c][col];
        #pragma unroll
        for (int k = 0; k < 24; k++) acc[k] += wp[k*CC + c] * xv;
    }
    size_t ob = (size_t)b*CHW + hw0;
    #pragma unroll
    for (int k = 0; k < 24; k++) {
        int o = og*24 + k;
        float v = acc[k] + bias[o];
        if (ADD_RES) v += res[ob + o*HWSZ + col];
        out[ob + o*HWSZ + col] = v;
    }
}

// ---------------- gelu(conv(a,w1)+b1) + gelu(conv(bI,w2)+b2) ----------------
__global__ __launch_bounds__(256) void dual_conv_gelu(const float* __restrict__ a, const float* __restrict__ bI,
        const float* __restrict__ w1, const float* __restrict__ b1,
        const float* __restrict__ w2, const float* __restrict__ b2,
        float* __restrict__ out) {
    __shared__ float as_[CC][64];
    __shared__ float bs_[CC][64];
    int b = blockIdx.y;
    int hw0 = blockIdx.x * 64;
    const float* ap = a  + (size_t)b*CHW + hw0;
    const float* bp = bI + (size_t)b*CHW + hw0;
    for (int i = threadIdx.x; i < CC*64; i += 256) {
        int c = i >> 6, col = i & 63;
        as_[c][col] = ap[c*HWSZ + col];
        bs_[c][col] = bp[c*HWSZ + col];
    }
    __syncthreads();
    int col = threadIdx.x & 63;
    int og = __builtin_amdgcn_readfirstlane((int)(threadIdx.x >> 6));
    const float* w1p = w1 + og*24*CC;
    const float* w2p = w2 + og*24*CC;
    float acc1[24], acc2[24];
    #pragma unroll
    for (int k = 0; k < 24; k++) { acc1[k] = 0.f; acc2[k] = 0.f; }
    #pragma unroll 4
    for (int c = 0; c < CC; c++) {
        float av = as_[c][col];
        float bv = bs_[c][col];
        #pragma unroll
        for (int k = 0; k < 24; k++) {
            acc1[k] += w1p[k*CC + c] * av;
            acc2[k] += w2p[k*CC + c] * bv;
        }
    }
    size_t ob = (size_t)b*CHW + hw0;
    #pragma unroll
    for (int k = 0; k < 24; k++) {
        int o = og*24 + k;
        out[ob + o*HWSZ + col] = gelu_f(acc1[k] + b1[o]) + gelu_f(acc2[k] + b2[o]);
    }
}

// ---------------- depthwise 3x3 SAME ----------------
__global__ __launch_bounds__(256) void dw3(const float* __restrict__ in, const float* __restrict__ wgt,
                                           const float* __restrict__ bias, float* __restrict__ out) {
    size_t idx = (size_t)blockIdx.x*256 + threadIdx.x;
    int hw = (int)(idx % HWSZ);
    int bc = (int)(idx / HWSZ);
    int w_ = hw % WW, h = hw / WW;
    int c  = bc % CC;
    const float* ip = in + (size_t)bc*HWSZ;
    const float* wp = wgt + c*9;
    float acc = bias[c];
    #pragma unroll
    for (int dy = -1; dy <= 1; dy++) {
        int hh = h + dy;
        if ((unsigned)hh < HH) {
            #pragma unroll
            for (int dx = -1; dx <= 1; dx++) {
                int ww2 = w_ + dx;
                if ((unsigned)ww2 < WW)
                    acc += ip[hh*WW + ww2] * wp[(dy+1)*3 + (dx+1)];
            }
        }
    }
    out[idx] = acc;
}

// ---------------- LIF along H (thread per (b,c,w); lanes span w -> coalesced) ----------------
__global__ __launch_bounds__(256) void lif_h(const float* __restrict__ in, float* __restrict__ out,
                                             const float* __restrict__ tau_p, const float* __restrict__ vth_p) {
    int t = blockIdx.x*256 + threadIdx.x;        // B*C*W threads
    int w_ = t % WW;
    int bc = t / WW;
    const float tau = *tau_p, vth = *vth_p;
    size_t base = (size_t)bc*HWSZ + w_;
    float u = 0.f, o = 0.f;
    for (int h = 0; h < HH; h++) {
        float xv = in[base + h*WW];
        u = xv + tau*u*(1.f - o);
        o = (u - vth > 0.f) ? 1.f : 0.f;
        out[base + h*WW] = o;
    }
}

// ---------------- LIF along W (LDS-staged rows, odd stride 57 -> conflict-free scan) ----------------
__global__ __launch_bounds__(256) void lif_w(const float* __restrict__ in, float* __restrict__ out,
                                             const float* __restrict__ tau_p, const float* __restrict__ vth_p) {
    __shared__ float tile[256*57];
    size_t base = (size_t)blockIdx.x * (256*WW);
    for (int i = threadIdx.x; i < 256*WW; i += 256) {
        int r = i / WW, cix = i % WW;
        tile[r*57 + cix] = in[base + i];
    }
    __syncthreads();
    const float tau = *tau_p, vth = *vth_p;
    float u = 0.f, o = 0.f;
    int off = threadIdx.x*57;
    for (int w_ = 0; w_ < WW; w_++) {
        float xv = tile[off + w_];
        u = xv + tau*u*(1.f - o);
        o = (u - vth > 0.f) ? 1.f : 0.f;
        tile[off + w_] = o;
    }
    __syncthreads();
    for (int i = threadIdx.x; i < 256*WW; i += 256) {
        int r = i / WW, cix = i % WW;
        out[base + i] = tile[r*57 + cix];
    }
}

// ---------------- fused MLP: out = x2 + f2( gelu( f1( gn(x2) ) ) ), chunked over hidden dim ----------------
__global__ __launch_bounds__(256) void mlp_fused(const float* __restrict__ x2, const float2* __restrict__ stats,
        const float* __restrict__ gam, const float* __restrict__ bet,
        const float* __restrict__ w1, const float* __restrict__ b1,
        const float* __restrict__ w2, const float* __restrict__ b2,
        float* __restrict__ out) {
    __shared__ float m1[CC][64];
    __shared__ float mc[CC][64];
    int b = blockIdx.y;
    int hw0 = blockIdx.x * 64;
    float2 st = stats[b];
    const float* xp = x2 + (size_t)b*CHW + hw0;
    for (int i = threadIdx.x; i < CC*64; i += 256) {
        int c = i >> 6, col = i & 63;
        float v = xp[c*HWSZ + col];
        m1[c][col] = (v - st.x)*st.y*gam[c] + bet[c];
    }
    __syncthreads();
    int col = threadIdx.x & 63;
    int og = __builtin_amdgcn_readfirstlane((int)(threadIdx.x >> 6));
    float accout[24];
    #pragma unroll
    for (int k = 0; k < 24; k++) accout[k] = 0.f;
    for (int ch = 0; ch < 4; ch++) {
        float a1[24];
        #pragma unroll
        for (int k = 0; k < 24; k++) a1[k] = b1[ch*96 + og*24 + k];
        const float* w1p = w1 + (size_t)(ch*96 + og*24)*CC;
        #pragma unroll 4
        for (int c = 0; c < CC; c++) {
            float mval = m1[c][col];
            #pragma unroll
            for (int k = 0; k < 24; k++) a1[k] += w1p[k*CC + c] * mval;
        }
        if (ch) __syncthreads();             // prev chunk phase-2 must finish reading mc
        #pragma unroll
        for (int k = 0; k < 24; k++) mc[og*24 + k][col] = gelu_f(a1[k]);
        __syncthreads();
        const float* w2p = w2 + (size_t)(og*24)*HD + ch*96;
        #pragma unroll 4
        for (int d = 0; d < 96; d++) {
            float mval = mc[d][col];
            #pragma unroll
            for (int k = 0; k < 24; k++) accout[k] += w2p[k*HD + d] * mval;
        }
    }
    size_t ob = (size_t)b*CHW + hw0;
    #pragma unroll
    for (int k = 0; k < 24; k++) {
        int o = og*24 + k;
        out[ob + o*HWSZ + col] = xp[o*HWSZ + col] + b2[o] + accout[k];
    }
}

extern "C" void kernel_launch(void* const* d_in, const int* in_sizes, int n_in,
                              void* d_out, int out_size, void* d_ws, size_t ws_size,
                              hipStream_t stream) {
    (void)in_sizes; (void)n_in; (void)out_size; (void)ws_size;
    const float* x    = (const float*)d_in[0];
    const float* n1g  = (const float*)d_in[1];
    const float* n1b  = (const float*)d_in[2];
    const float* c1w  = (const float*)d_in[3];
    const float* c1b  = (const float*)d_in[4];
    const float* g1g  = (const float*)d_in[5];
    const float* g1b  = (const float*)d_in[6];
    const float* dww  = (const float*)d_in[7];
    const float* dwb  = (const float*)d_in[8];
    const float* g2g  = (const float*)d_in[9];
    const float* g2b  = (const float*)d_in[10];
    const float* tau1 = (const float*)d_in[11];
    const float* vth1 = (const float*)d_in[12];
    const float* tau2 = (const float*)d_in[13];
    const float* vth2 = (const float*)d_in[14];
    const float* c21w = (const float*)d_in[15];
    const float* c21b = (const float*)d_in[16];
    const float* c22w = (const float*)d_in[17];
    const float* c22b = (const float*)d_in[18];
    const float* g3g  = (const float*)d_in[19];
    const float* g3b  = (const float*)d_in[20];
    const float* c3w  = (const float*)d_in[21];
    const float* c3b  = (const float*)d_in[22];
    const float* n2g  = (const float*)d_in[23];
    const float* n2b  = (const float*)d_in[24];
    const float* f1w  = (const float*)d_in[25];
    const float* f1b  = (const float*)d_in[26];
    const float* f2w  = (const float*)d_in[27];
    const float* f2b  = (const float*)d_in[28];
    float* out = (float*)d_out;

    float*  buf0  = (float*)d_ws;
    float*  buf1  = buf0 + NTOT;
    float2* part  = (float2*)(buf1 + NTOT);
    float2* stats = part + BB*S_SPLIT;

    dim3 gStat(S_SPLIT, BB);
    dim3 gConv(HWSZ/64, BB);
    int gApply = (int)(NTOT/4/256);   // 18816
    int gElem  = (int)(NTOT/256);     // 75264
    int gLif   = (BB*CC*WW)/256;      // 1344

    // ---- LIF module ----
    gn_partial<<<gStat,256,0,stream>>>(x, part);                 // n1 stats on x
    gn_final  <<<1,64,0,stream>>>(part, stats);
    conv96<true,false><<<gConv,256,0,stream>>>(x, c1w, c1b, stats, n1g, n1b, nullptr, buf0);  // t1
    gn_partial<<<gStat,256,0,stream>>>(buf0, part);              // g1 stats
    gn_final  <<<1,64,0,stream>>>(part, stats);
    gn_apply<true><<<gApply,256,0,stream>>>(buf0, stats, g1g, g1b);   // h1 = gelu(gn(t1))
    dw3<<<gElem,256,0,stream>>>(buf0, dww, dwb, buf1);           // t2
    gn_partial<<<gStat,256,0,stream>>>(buf1, part);              // g2 stats
    gn_final  <<<1,64,0,stream>>>(part, stats);
    gn_apply<true><<<gApply,256,0,stream>>>(buf1, stats, g2g, g2b);   // h2
    lif_h<<<gLif,256,0,stream>>>(buf1, buf0, tau1, vth1);        // x_lr
    lif_w<<<gLif,256,0,stream>>>(buf1, out,  tau2, vth2);        // x_td (d_out as scratch)
    dual_conv_gelu<<<gConv,256,0,stream>>>(buf0, out, c21w, c21b, c22w, c22b, buf1);  // h3
    gn_partial<<<gStat,256,0,stream>>>(buf1, part);              // g3 stats
    gn_final  <<<1,64,0,stream>>>(part, stats);
    conv96<true,true><<<gConv,256,0,stream>>>(buf1, c3w, c3b, stats, g3g, g3b, x, buf0);  // x2 = x + conv3(gn(h3))
    // ---- MLP branch ----
    gn_partial<<<gStat,256,0,stream>>>(buf0, part);              // n2 stats on x2
    gn_final  <<<1,64,0,stream>>>(part, stats);
    mlp_fused<<<gConv,256,0,stream>>>(buf0, stats, n2g, n2b, f1w, f1b, f2w, f2b, out);
}

// Round 2
// 753.549 us; speedup vs baseline: 1.9940x; 1.9940x over previous
//
#include <hip/hip_runtime.h>

#define BB 64
#define CC 96
#define HH 56
#define WW 56
#define HWSZ (HH*WW)          // 3136
#define CHW (CC*HWSZ)         // 301056
#define NTOT ((size_t)BB*CHW) // 19267584
#define S_SPLIT 32
#define CHUNK (CHW/S_SPLIT)   // 9408
#define HD 384
#define NP 104                // LDS row pitch (ushorts): 208B rows, 16B-aligned

typedef float f32x4  __attribute__((ext_vector_type(4)));
typedef short bf16x8 __attribute__((ext_vector_type(8)));

__device__ __forceinline__ unsigned short f2bf(float f) {
    unsigned int u = __float_as_uint(f);
    u = (u + 0x7FFFu + ((u >> 16) & 1u)) >> 16;   // RNE
    return (unsigned short)u;
}
__device__ __forceinline__ float gelu_f(float x) {
    return 0.5f*x*(1.0f + erff(x*0.70710678118654752f));
}
__device__ __forceinline__ bf16x8 ldfrag(const unsigned short* p) {
    return *reinterpret_cast<const bf16x8*>(p);
}

// ---------------- GroupNorm(1,C) stats: two-stage deterministic reduction ----------------
__global__ __launch_bounds__(256) void gn_partial(const float* __restrict__ in, float2* __restrict__ part) {
    int b = blockIdx.y, s = blockIdx.x;
    const float* p = in + (size_t)b*CHW + (size_t)s*CHUNK;
    float sum = 0.f, sq = 0.f;
    for (int i = threadIdx.x; i < CHUNK; i += 256) {
        float v = p[i];
        sum += v; sq += v*v;
    }
    for (int off = 32; off > 0; off >>= 1) {
        sum += __shfl_down(sum, off);
        sq  += __shfl_down(sq,  off);
    }
    __shared__ float2 red[4];
    int wid = threadIdx.x >> 6, lane = threadIdx.x & 63;
    if (lane == 0) red[wid] = make_float2(sum, sq);
    __syncthreads();
    if (threadIdx.x == 0) {
        for (int i = 1; i < 4; i++) { sum += red[i].x; sq += red[i].y; }
        part[b*S_SPLIT + s] = make_float2(sum, sq);
    }
}

__global__ void gn_final(const float2* __restrict__ part, float2* __restrict__ stats) {
    int b = threadIdx.x;
    if (b >= BB) return;
    float s = 0.f, q = 0.f;
    for (int i = 0; i < S_SPLIT; i++) { float2 v = part[b*S_SPLIT + i]; s += v.x; q += v.y; }
    float mean = s / (float)CHW;
    float var  = q / (float)CHW - mean*mean;
    float rstd = rsqrtf(var + 1e-5f);
    stats[b] = make_float2(mean, rstd);
}

// ---------------- normalize (+optional gelu), in place, float4 ----------------
template<bool G>
__global__ __launch_bounds__(256) void gn_apply(float* __restrict__ t, const float2* __restrict__ stats,
                                                const float* __restrict__ gam, const float* __restrict__ bet) {
    int i = blockIdx.x*256 + threadIdx.x;        // over NTOT/4
    int b = i / (CHW/4);
    int c = (i / (HWSZ/4)) % CC;
    float2 st = stats[b];
    float g  = gam[c]*st.y;
    float bb = bet[c] - st.x*g;
    float4 v = reinterpret_cast<float4*>(t)[i];
    v.x = v.x*g + bb; v.y = v.y*g + bb; v.z = v.z*g + bb; v.w = v.w*g + bb;
    if (G) { v.x = gelu_f(v.x); v.y = gelu_f(v.y); v.z = gelu_f(v.z); v.w = gelu_f(v.w); }
    reinterpret_cast<float4*>(t)[i] = v;
}

// ---------------- 1x1 conv via MFMA: D[96 x 64] = W[96x96] * X[96 x 64] per block ----------------
template<bool PRE_NORM, bool ADD_RES>
__global__ __launch_bounds__(256) void conv96_mfma(const float* __restrict__ in,
        const float* __restrict__ wgt, const float* __restrict__ bias,
        const float2* __restrict__ stats, const float* __restrict__ gam, const float* __restrict__ bet,
        const float* __restrict__ res, float* __restrict__ out) {
    __shared__ unsigned short xs[64][NP];   // X^T tile: xs[n][c]
    __shared__ unsigned short ws[CC][NP];   // W tile:  ws[o][c]
    int b = blockIdx.y;
    int hw0 = blockIdx.x * 64;
    int tid = threadIdx.x;
    const float* ip = in + (size_t)b*CHW + hw0;
    float mean = 0.f, rstd = 1.f;
    if (PRE_NORM) { float2 st = stats[b]; mean = st.x; rstd = st.y; }
    for (int i = tid; i < CC*64; i += 256) {
        int c = i >> 6, col = i & 63;
        float v = ip[c*HWSZ + col];
        if (PRE_NORM) v = (v - mean)*rstd*gam[c] + bet[c];
        xs[col][c] = f2bf(v);
    }
    for (int i = tid; i < CC*CC; i += 256) {
        int r = i/CC, c = i - r*CC;
        ws[r][c] = f2bf(wgt[i]);
    }
    __syncthreads();
    int lane = tid & 63, wid = tid >> 6;
    int ln = lane & 15, k0 = (lane >> 4)*8, n0 = wid*16;
    f32x4 acc[6];
    #pragma unroll
    for (int t = 0; t < 6; t++) acc[t] = (f32x4){0.f,0.f,0.f,0.f};
    #pragma unroll
    for (int ks = 0; ks < 3; ks++) {
        bf16x8 bf = ldfrag(&xs[n0+ln][ks*32+k0]);
        #pragma unroll
        for (int tm = 0; tm < 6; tm++) {
            bf16x8 af = ldfrag(&ws[tm*16+ln][ks*32+k0]);
            acc[tm] = __builtin_amdgcn_mfma_f32_16x16x32_bf16(af, bf, acc[tm], 0, 0, 0);
        }
    }
    size_t ob = (size_t)b*CHW + hw0;
    int r0 = (lane >> 4)*4;
    #pragma unroll
    for (int tm = 0; tm < 6; tm++) {
        #pragma unroll
        for (int r = 0; r < 4; r++) {
            int o = tm*16 + r0 + r;
            float v = acc[tm][r] + bias[o];
            size_t idx = ob + (size_t)o*HWSZ + n0 + ln;
            if (ADD_RES) v += res[idx];
            out[idx] = v;
        }
    }
}

// ---------------- gelu(conv(a,w1)+b1) + gelu(conv(bI,w2)+b2), MFMA ----------------
__global__ __launch_bounds__(256) void dual_mfma(const float* __restrict__ a, const float* __restrict__ bI,
        const float* __restrict__ w1, const float* __restrict__ b1,
        const float* __restrict__ w2, const float* __restrict__ b2,
        float* __restrict__ out) {
    __shared__ unsigned short xa[64][NP];
    __shared__ unsigned short xb[64][NP];
    __shared__ unsigned short ws[CC][NP];
    int b = blockIdx.y;
    int hw0 = blockIdx.x * 64;
    int tid = threadIdx.x;
    const float* ap = a  + (size_t)b*CHW + hw0;
    const float* bp = bI + (size_t)b*CHW + hw0;
    for (int i = tid; i < CC*64; i += 256) {
        int c = i >> 6, col = i & 63;
        xa[col][c] = f2bf(ap[c*HWSZ + col]);
        xb[col][c] = f2bf(bp[c*HWSZ + col]);
    }
    for (int i = tid; i < CC*CC; i += 256) {
        int r = i/CC, c = i - r*CC;
        ws[r][c] = f2bf(w1[i]);
    }
    __syncthreads();
    int lane = tid & 63, wid = tid >> 6;
    int ln = lane & 15, k0 = (lane >> 4)*8, n0 = wid*16;
    f32x4 acc1[6], acc2[6];
    #pragma unroll
    for (int t = 0; t < 6; t++) { acc1[t] = (f32x4){0.f,0.f,0.f,0.f}; acc2[t] = (f32x4){0.f,0.f,0.f,0.f}; }
    #pragma unroll
    for (int ks = 0; ks < 3; ks++) {
        bf16x8 bf = ldfrag(&xa[n0+ln][ks*32+k0]);
        #pragma unroll
        for (int tm = 0; tm < 6; tm++) {
            bf16x8 af = ldfrag(&ws[tm*16+ln][ks*32+k0]);
            acc1[tm] = __builtin_amdgcn_mfma_f32_16x16x32_bf16(af, bf, acc1[tm], 0, 0, 0);
        }
    }
    __syncthreads();
    for (int i = tid; i < CC*CC; i += 256) {
        int r = i/CC, c = i - r*CC;
        ws[r][c] = f2bf(w2[i]);
    }
    __syncthreads();
    #pragma unroll
    for (int ks = 0; ks < 3; ks++) {
        bf16x8 bf = ldfrag(&xb[n0+ln][ks*32+k0]);
        #pragma unroll
        for (int tm = 0; tm < 6; tm++) {
            bf16x8 af = ldfrag(&ws[tm*16+ln][ks*32+k0]);
            acc2[tm] = __builtin_amdgcn_mfma_f32_16x16x32_bf16(af, bf, acc2[tm], 0, 0, 0);
        }
    }
    size_t ob = (size_t)b*CHW + hw0;
    int r0 = (lane >> 4)*4;
    #pragma unroll
    for (int tm = 0; tm < 6; tm++) {
        #pragma unroll
        for (int r = 0; r < 4; r++) {
            int o = tm*16 + r0 + r;
            size_t idx = ob + (size_t)o*HWSZ + n0 + ln;
            out[idx] = gelu_f(acc1[tm][r] + b1[o]) + gelu_f(acc2[tm][r] + b2[o]);
        }
    }
}

// ---------------- depthwise 3x3 SAME ----------------
__global__ __launch_bounds__(256) void dw3(const float* __restrict__ in, const float* __restrict__ wgt,
                                           const float* __restrict__ bias, float* __restrict__ out) {
    size_t idx = (size_t)blockIdx.x*256 + threadIdx.x;
    int hw = (int)(idx % HWSZ);
    int bc = (int)(idx / HWSZ);
    int w_ = hw % WW, h = hw / WW;
    int c  = bc % CC;
    const float* ip = in + (size_t)bc*HWSZ;
    const float* wp = wgt + c*9;
    float acc = bias[c];
    #pragma unroll
    for (int dy = -1; dy <= 1; dy++) {
        int hh = h + dy;
        if ((unsigned)hh < HH) {
            #pragma unroll
            for (int dx = -1; dx <= 1; dx++) {
                int ww2 = w_ + dx;
                if ((unsigned)ww2 < WW)
                    acc += ip[hh*WW + ww2] * wp[(dy+1)*3 + (dx+1)];
            }
        }
    }
    out[idx] = acc;
}

// ---------------- LIF along H ----------------
__global__ __launch_bounds__(256) void lif_h(const float* __restrict__ in, float* __restrict__ out,
                                             const float* __restrict__ tau_p, const float* __restrict__ vth_p) {
    int t = blockIdx.x*256 + threadIdx.x;        // B*C*W threads
    int w_ = t % WW;
    int bc = t / WW;
    const float tau = *tau_p, vth = *vth_p;
    size_t base = (size_t)bc*HWSZ + w_;
    float u = 0.f, o = 0.f;
    for (int h = 0; h < HH; h++) {
        float xv = in[base + h*WW];
        u = xv + tau*u*(1.f - o);
        o = (u - vth > 0.f) ? 1.f : 0.f;
        out[base + h*WW] = o;
    }
}

// ---------------- LIF along W ----------------
__global__ __launch_bounds__(256) void lif_w(const float* __restrict__ in, float* __restrict__ out,
                                             const float* __restrict__ tau_p, const float* __restrict__ vth_p) {
    __shared__ float tile[256*57];
    size_t base = (size_t)blockIdx.x * (256*WW);
    for (int i = threadIdx.x; i < 256*WW; i += 256) {
        int r = i / WW, cix = i % WW;
        tile[r*57 + cix] = in[base + i];
    }
    __syncthreads();
    const float tau = *tau_p, vth = *vth_p;
    float u = 0.f, o = 0.f;
    int off = threadIdx.x*57;
    for (int w_ = 0; w_ < WW; w_++) {
        float xv = tile[off + w_];
        u = xv + tau*u*(1.f - o);
        o = (u - vth > 0.f) ? 1.f : 0.f;
        tile[off + w_] = o;
    }
    __syncthreads();
    for (int i = threadIdx.x; i < 256*WW; i += 256) {
        int r = i / WW, cix = i % WW;
        out[base + i] = tile[r*57 + cix];
    }
}

// ---------------- fused MLP (MFMA): out = x2 + f2( gelu( f1( gn(x2) ) ) ), chunked over hidden ----------------
__global__ __launch_bounds__(256) void mlp_mfma(const float* __restrict__ x2, const float2* __restrict__ stats,
        const float* __restrict__ gam, const float* __restrict__ bet,
        const float* __restrict__ w1, const float* __restrict__ b1,
        const float* __restrict__ w2, const float* __restrict__ b2,
        float* __restrict__ out) {
    __shared__ unsigned short xs[64][NP];   // gn(x2)^T tile
    __shared__ unsigned short mc[64][NP];   // mid chunk^T: mc[n][d_local]
    __shared__ unsigned short ws[CC][NP];   // weight chunk staging
    int b = blockIdx.y;
    int hw0 = blockIdx.x * 64;
    int tid = threadIdx.x;
    float2 st = stats[b];
    const float* xp = x2 + (size_t)b*CHW + hw0;
    for (int i = tid; i < CC*64; i += 256) {
        int c = i >> 6, col = i & 63;
        float v = xp[c*HWSZ + col];
        xs[col][c] = f2bf((v - st.x)*st.y*gam[c] + bet[c]);
    }
    int lane = tid & 63, wid = tid >> 6;
    int ln = lane & 15, k0 = (lane >> 4)*8, n0 = wid*16;
    int r0 = (lane >> 4)*4;
    f32x4 accout[6];
    #pragma unroll
    for (int t = 0; t < 6; t++) accout[t] = (f32x4){0.f,0.f,0.f,0.f};
    for (int ch = 0; ch < 4; ch++) {
        __syncthreads();                          // xs ready (ch0) / mc+ws reuse safe (ch>0)
        for (int i = tid; i < CC*CC; i += 256) {  // w1 chunk rows [ch*96, ch*96+96)
            ws[i/CC][i - (i/CC)*CC] = f2bf(w1[ch*CC*CC + i]);
        }
        __syncthreads();
        f32x4 acc1[6];
        #pragma unroll
        for (int t = 0; t < 6; t++) acc1[t] = (f32x4){0.f,0.f,0.f,0.f};
        #pragma unroll
        for (int ks = 0; ks < 3; ks++) {
            bf16x8 bf = ldfrag(&xs[n0+ln][ks*32+k0]);
            #pragma unroll
            for (int tm = 0; tm < 6; tm++) {
                bf16x8 af = ldfrag(&ws[tm*16+ln][ks*32+k0]);
                acc1[tm] = __builtin_amdgcn_mfma_f32_16x16x32_bf16(af, bf, acc1[tm], 0, 0, 0);
            }
        }
        __syncthreads();                          // all waves done reading ws (and mc from prev ch)
        // write mid chunk transposed: mc[n][d_local], 4 consecutive d per (tm)
        #pragma unroll
        for (int tm = 0; tm < 6; tm++) {
            int d0 = tm*16 + r0;
            unsigned int lo, hi;
            unsigned short h0 = f2bf(gelu_f(acc1[tm][0] + b1[ch*CC + d0 + 0]));
            unsigned short h1 = f2bf(gelu_f(acc1[tm][1] + b1[ch*CC + d0 + 1]));
            unsigned short h2 = f2bf(gelu_f(acc1[tm][2] + b1[ch*CC + d0 + 2]));
            unsigned short h3 = f2bf(gelu_f(acc1[tm][3] + b1[ch*CC + d0 + 3]));
            lo = (unsigned int)h0 | ((unsigned int)h1 << 16);
            hi = (unsigned int)h2 | ((unsigned int)h3 << 16);
            *reinterpret_cast<uint2*>(&mc[n0+ln][d0]) = make_uint2(lo, hi);
        }
        for (int i = tid; i < CC*CC; i += 256) {  // w2 chunk cols [ch*96, ch*96+96)
            int r = i/CC, c = i - r*CC;
            ws[r][c] = f2bf(w2[r*HD + ch*CC + c]);
        }
        __syncthreads();
        #pragma unroll
        for (int ks = 0; ks < 3; ks++) {
            bf16x8 bf = ldfrag(&mc[n0+ln][ks*32+k0]);
            #pragma unroll
            for (int tm = 0; tm < 6; tm++) {
                bf16x8 af = ldfrag(&ws[tm*16+ln][ks*32+k0]);
                accout[tm] = __builtin_amdgcn_mfma_f32_16x16x32_bf16(af, bf, accout[tm], 0, 0, 0);
            }
        }
    }
    size_t ob = (size_t)b*CHW + hw0;
    #pragma unroll
    for (int tm = 0; tm < 6; tm++) {
        #pragma unroll
        for (int r = 0; r < 4; r++) {
            int o = tm*16 + r0 + r;
            size_t idx = ob + (size_t)o*HWSZ + n0 + ln;
            out[idx] = xp[(size_t)o*HWSZ + n0 + ln] + b2[o] + accout[tm][r];
        }
    }
}

extern "C" void kernel_launch(void* const* d_in, const int* in_sizes, int n_in,
                              void* d_out, int out_size, void* d_ws, size_t ws_size,
                              hipStream_t stream) {
    (void)in_sizes; (void)n_in; (void)out_size; (void)ws_size;
    const float* x    = (const float*)d_in[0];
    const float* n1g  = (const float*)d_in[1];
    const float* n1b  = (const float*)d_in[2];
    const float* c1w  = (const float*)d_in[3];
    const float* c1b  = (const float*)d_in[4];
    const float* g1g  = (const float*)d_in[5];
    const float* g1b  = (const float*)d_in[6];
    const float* dww  = (const float*)d_in[7];
    const float* dwb  = (const float*)d_in[8];
    const float* g2g  = (const float*)d_in[9];
    const float* g2b  = (const float*)d_in[10];
    const float* tau1 = (const float*)d_in[11];
    const float* vth1 = (const float*)d_in[12];
    const float* tau2 = (const float*)d_in[13];
    const float* vth2 = (const float*)d_in[14];
    const float* c21w = (const float*)d_in[15];
    const float* c21b = (const float*)d_in[16];
    const float* c22w = (const float*)d_in[17];
    const float* c22b = (const float*)d_in[18];
    const float* g3g  = (const float*)d_in[19];
    const float* g3b  = (const float*)d_in[20];
    const float* c3w  = (const float*)d_in[21];
    const float* c3b  = (const float*)d_in[22];
    const float* n2g  = (const float*)d_in[23];
    const float* n2b  = (const float*)d_in[24];
    const float* f1w  = (const float*)d_in[25];
    const float* f1b  = (const float*)d_in[26];
    const float* f2w  = (const float*)d_in[27];
    const float* f2b  = (const float*)d_in[28];
    float* out = (float*)d_out;

    float*  buf0  = (float*)d_ws;
    float*  buf1  = buf0 + NTOT;
    float2* part  = (float2*)(buf1 + NTOT);
    float2* stats = part + BB*S_SPLIT;

    dim3 gStat(S_SPLIT, BB);
    dim3 gConv(HWSZ/64, BB);
    int gApply = (int)(NTOT/4/256);   // 18816
    int gElem  = (int)(NTOT/256);     // 75264
    int gLif   = (BB*CC*WW)/256;      // 1344

    // ---- LIF module ----
    gn_partial<<<gStat,256,0,stream>>>(x, part);                 // n1 stats on x
    gn_final  <<<1,64,0,stream>>>(part, stats);
    conv96_mfma<true,false><<<gConv,256,0,stream>>>(x, c1w, c1b, stats, n1g, n1b, nullptr, buf0);  // t1
    gn_partial<<<gStat,256,0,stream>>>(buf0, part);              // g1 stats
    gn_final  <<<1,64,0,stream>>>(part, stats);
    gn_apply<true><<<gApply,256,0,stream>>>(buf0, stats, g1g, g1b);   // h1 = gelu(gn(t1))
    dw3<<<gElem,256,0,stream>>>(buf0, dww, dwb, buf1);           // t2
    gn_partial<<<gStat,256,0,stream>>>(buf1, part);              // g2 stats
    gn_final  <<<1,64,0,stream>>>(part, stats);
    gn_apply<true><<<gApply,256,0,stream>>>(buf1, stats, g2g, g2b);   // h2
    lif_h<<<gLif,256,0,stream>>>(buf1, buf0, tau1, vth1);        // x_lr
    lif_w<<<gLif,256,0,stream>>>(buf1, out,  tau2, vth2);        // x_td (d_out as scratch)
    dual_mfma<<<gConv,256,0,stream>>>(buf0, out, c21w, c21b, c22w, c22b, buf1);  // h3
    gn_partial<<<gStat,256,0,stream>>>(buf1, part);              // g3 stats
    gn_final  <<<1,64,0,stream>>>(part, stats);
    conv96_mfma<true,true><<<gConv,256,0,stream>>>(buf1, c3w, c3b, stats, g3g, g3b, x, buf0);  // x2
    // ---- MLP branch ----
    gn_partial<<<gStat,256,0,stream>>>(buf0, part);              // n2 stats on x2
    gn_final  <<<1,64,0,stream>>>(part, stats);
    mlp_mfma<<<gConv,256,0,stream>>>(buf0, stats, n2g, n2b, f1w, f1b, f2w, f2b, out);
}

// Round 3
// 505.750 us; speedup vs baseline: 2.9710x; 1.4900x over previous
//
#include <hip/hip_runtime.h>

#define BB 64
#define CC 96
#define HH 56
#define WW 56
#define HWSZ (HH*WW)          // 3136
#define CHW (CC*HWSZ)         // 301056
#define NTOT ((size_t)BB*CHW) // 19267584
#define S_SPLIT 32
#define CHUNK (CHW/S_SPLIT)   // 9408
#define HD 384
#define NP 104                // LDS row pitch (ushorts): 208B rows, 16B-aligned

typedef float f32x4  __attribute__((ext_vector_type(4)));
typedef short bf16x8 __attribute__((ext_vector_type(8)));
typedef unsigned short ushort_t;

__device__ __forceinline__ unsigned short f2bf(float f) {
    unsigned int u = __float_as_uint(f);
    u = (u + 0x7FFFu + ((u >> 16) & 1u)) >> 16;   // RNE
    return (unsigned short)u;
}
__device__ __forceinline__ float bf2f(unsigned short u) {
    return __uint_as_float(((unsigned int)u) << 16);
}
// tanh-approx GELU: 7 VALU ops (1 exp2, 1 rcp). |err| vs exact erf-gelu ~1e-3.
__device__ __forceinline__ float gelu_t(float x) {
    float s = x*x;
    float q = __builtin_fmaf(s, 0.102943f, 2.3021953f) * x;   // 2y*log2e
    float t = exp2f(q);
    float r = __builtin_amdgcn_rcpf(1.0f + t);
    return __builtin_fmaf(-x, r, x);                          // x - x/(1+e^{2y})
}
__device__ __forceinline__ bf16x8 ldfrag(const unsigned short* p) {
    return *reinterpret_cast<const bf16x8*>(p);
}

// ================= weight pre-convert (f32 -> bf16), once =================
__global__ __launch_bounds__(256) void wconv(const float* __restrict__ c1w, const float* __restrict__ c21w,
        const float* __restrict__ c22w, const float* __restrict__ c3w,
        const float* __restrict__ f1w, const float* __restrict__ f2w,
        unsigned short* __restrict__ wbf) {
    int i = blockIdx.x*256 + threadIdx.x;           // 110592 total
    if (i >= 110592) return;
    float v;
    if      (i <  9216) v = c1w[i];
    else if (i < 18432) v = c21w[i-9216];
    else if (i < 27648) v = c22w[i-18432];
    else if (i < 36864) v = c3w[i-27648];
    else if (i < 73728) v = f1w[i-36864];
    else                v = f2w[i-73728];
    wbf[i] = f2bf(v);
}

// ================= GN stats on x (only standalone stats pass) =================
__global__ __launch_bounds__(256) void gn_partial(const float* __restrict__ in, float2* __restrict__ part) {
    int b = blockIdx.y, s = blockIdx.x;
    const float* p = in + (size_t)b*CHW + (size_t)s*CHUNK;
    float sum = 0.f, sq = 0.f;
    for (int i = threadIdx.x; i < CHUNK; i += 256) {
        float v = p[i];
        sum += v; sq += v*v;
    }
    for (int off = 32; off > 0; off >>= 1) {
        sum += __shfl_down(sum, off);
        sq  += __shfl_down(sq,  off);
    }
    __shared__ float2 red[4];
    int wid = threadIdx.x >> 6, lane = threadIdx.x & 63;
    if (lane == 0) red[wid] = make_float2(sum, sq);
    __syncthreads();
    if (threadIdx.x == 0) {
        for (int i = 1; i < 4; i++) { sum += red[i].x; sq += red[i].y; }
        part[b*S_SPLIT + s] = make_float2(sum, sq);
    }
}

template<int NPART>
__global__ void gn_final(const float2* __restrict__ part, float2* __restrict__ stats) {
    int b = threadIdx.x;
    if (b >= BB) return;
    float s = 0.f, q = 0.f;
    for (int i = 0; i < NPART; i++) { float2 v = part[b*NPART + i]; s += v.x; q += v.y; }
    float mean = s / (float)CHW;
    float var  = q / (float)CHW - mean*mean;
    stats[b] = make_float2(mean, rsqrtf(var + 1e-5f));
}

// ================= batch-paired 1x1 conv with pre-norm + stats epilogue =================
// IN_BF: input bf16 else f32.  OUT_RES: out = res + acc (f32) else out bf16.
template<bool IN_BF, bool OUT_RES>
__global__ __launch_bounds__(256) void convk(const void* __restrict__ in_,
        const unsigned short* __restrict__ wbf, const float* __restrict__ bias,
        const float2* __restrict__ st_in, const float* __restrict__ gam, const float* __restrict__ bet,
        const float* __restrict__ res, void* __restrict__ out_, float2* __restrict__ part) {
    __shared__ unsigned short xs[128][NP];
    __shared__ float gml[CC], btl[CC];
    __shared__ float2 red[8];
    int tid = threadIdx.x;
    int b0 = blockIdx.y, b1 = b0 + 32;
    int hw0 = blockIdx.x * 64;
    if (tid < CC) { gml[tid] = gam[tid]; btl[tid] = bet[tid]; }
    float2 st0 = st_in[b0], st1 = st_in[b1];
    __syncthreads();
    int col = tid & 63;
    for (int c4 = (tid >> 6)*4; c4 < CC; c4 += 16) {
        unsigned int pk0[2], pk1[2];
        #pragma unroll
        for (int j = 0; j < 4; j++) {
            int c = c4 + j;
            size_t off0 = (size_t)b0*CHW + (size_t)c*HWSZ + hw0 + col;
            size_t off1 = (size_t)b1*CHW + (size_t)c*HWSZ + hw0 + col;
            float r0 = IN_BF ? bf2f(((const unsigned short*)in_)[off0]) : ((const float*)in_)[off0];
            float r1 = IN_BF ? bf2f(((const unsigned short*)in_)[off1]) : ((const float*)in_)[off1];
            float a0 = st0.y * gml[c], b0c = __builtin_fmaf(-st0.x, a0, btl[c]);
            float a1 = st1.y * gml[c], b1c = __builtin_fmaf(-st1.x, a1, btl[c]);
            unsigned short h0 = f2bf(__builtin_fmaf(r0, a0, b0c));
            unsigned short h1 = f2bf(__builtin_fmaf(r1, a1, b1c));
            if (j < 2) { if (j == 0) { pk0[0] = h0; pk1[0] = h1; } else { pk0[0] |= (unsigned int)h0 << 16; pk1[0] |= (unsigned int)h1 << 16; } }
            else       { if (j == 2) { pk0[1] = h0; pk1[1] = h1; } else { pk0[1] |= (unsigned int)h0 << 16; pk1[1] |= (unsigned int)h1 << 16; } }
        }
        *reinterpret_cast<uint2*>(&xs[col][c4])      = make_uint2(pk0[0], pk0[1]);
        *reinterpret_cast<uint2*>(&xs[64+col][c4])   = make_uint2(pk1[0], pk1[1]);
    }
    __syncthreads();
    int lane = tid & 63, wid = tid >> 6;
    int ln = lane & 15, k0 = (lane >> 4)*8, n0 = wid*16;
    f32x4 a0[6], a1[6];
    #pragma unroll
    for (int t = 0; t < 6; t++) { a0[t] = (f32x4){0,0,0,0}; a1[t] = (f32x4){0,0,0,0}; }
    int wro = ln*CC + k0;
    #pragma unroll
    for (int ks = 0; ks < 3; ks++) {
        bf16x8 bf0 = ldfrag(&xs[n0+ln][ks*32+k0]);
        bf16x8 bf1 = ldfrag(&xs[64+n0+ln][ks*32+k0]);
        #pragma unroll
        for (int tm = 0; tm < 6; tm++) {
            bf16x8 af = ldfrag(wbf + (size_t)tm*16*CC + ks*32 + wro);
            a0[tm] = __builtin_amdgcn_mfma_f32_16x16x32_bf16(af, bf0, a0[tm], 0, 0, 0);
            a1[tm] = __builtin_amdgcn_mfma_f32_16x16x32_bf16(af, bf1, a1[tm], 0, 0, 0);
        }
    }
    int r0i = (lane >> 4)*4;
    size_t ob0 = (size_t)b0*CHW + hw0 + n0 + ln;
    size_t ob1 = (size_t)b1*CHW + hw0 + n0 + ln;
    float s0 = 0.f, q0 = 0.f, s1 = 0.f, q1 = 0.f;
    #pragma unroll
    for (int tm = 0; tm < 6; tm++) {
        #pragma unroll
        for (int r = 0; r < 4; r++) {
            int o = tm*16 + r0i + r;
            size_t i0 = ob0 + (size_t)o*HWSZ, i1 = ob1 + (size_t)o*HWSZ;
            float v0 = a0[tm][r] + bias[o];
            float v1 = a1[tm][r] + bias[o];
            if (OUT_RES) { v0 += res[i0]; v1 += res[i1];
                           ((float*)out_)[i0] = v0; ((float*)out_)[i1] = v1; }
            else         { ((unsigned short*)out_)[i0] = f2bf(v0); ((unsigned short*)out_)[i1] = f2bf(v1); }
            s0 += v0; q0 += v0*v0; s1 += v1; q1 += v1*v1;
        }
    }
    for (int off = 32; off > 0; off >>= 1) {
        s0 += __shfl_down(s0, off); q0 += __shfl_down(q0, off);
        s1 += __shfl_down(s1, off); q1 += __shfl_down(q1, off);
    }
    if (lane == 0) { red[wid] = make_float2(s0, q0); red[4+wid] = make_float2(s1, q1); }
    __syncthreads();
    if (tid == 0) {
        float S0=0,Q0=0,S1=0,Q1=0;
        for (int i = 0; i < 4; i++) { S0 += red[i].x; Q0 += red[i].y; S1 += red[4+i].x; Q1 += red[4+i].y; }
        part[b0*49 + blockIdx.x] = make_float2(S0, Q0);
        part[b1*49 + blockIdx.x] = make_float2(S1, Q1);
    }
}

// ================= depthwise 3x3: fused gelu(gn(t1)) on stage-in, stats epilogue =================
__global__ __launch_bounds__(256) void dw_fused(const unsigned short* __restrict__ t1,
        const float* __restrict__ dww, const float* __restrict__ dwb,
        const float2* __restrict__ st_in, const float* __restrict__ gam, const float* __restrict__ bet,
        unsigned short* __restrict__ t2, float2* __restrict__ part) {
    __shared__ float tile[HH*57];
    __shared__ float2 red[4];
    int bc = blockIdx.x;
    int b = bc / CC, c = bc - b*CC;
    int tid = threadIdx.x;
    float2 st = st_in[b];
    float ga = gam[c]*st.y;
    float bb = __builtin_fmaf(-st.x, ga, bet[c]);
    const unsigned short* ip = t1 + (size_t)bc*HWSZ;
    for (int i = tid; i < HWSZ; i += 256) {
        float v = __builtin_fmaf(bf2f(ip[i]), ga, bb);
        tile[(i/WW)*57 + (i%WW)] = gelu_t(v);
    }
    __syncthreads();
    float w00=dww[c*9+0],w01=dww[c*9+1],w02=dww[c*9+2],
          w10=dww[c*9+3],w11=dww[c*9+4],w12=dww[c*9+5],
          w20=dww[c*9+6],w21=dww[c*9+7],w22=dww[c*9+8];
    float bs = dwb[c];
    unsigned short* op = t2 + (size_t)bc*HWSZ;
    float s = 0.f, q = 0.f;
    for (int i = tid; i < HWSZ; i += 256) {
        int h = i/WW, w_ = i - h*WW;
        float acc = bs;
        int up = h > 0, dn = h < HH-1, lf = w_ > 0, rt = w_ < WW-1;
        const float* rm = &tile[(h-1)*57 + w_];
        const float* r0p = &tile[h*57 + w_];
        const float* rp = &tile[(h+1)*57 + w_];
        if (up) { if (lf) acc += rm[-1]*w00; acc += rm[0]*w01; if (rt) acc += rm[1]*w02; }
        if (lf) acc += r0p[-1]*w10;
        acc += r0p[0]*w11;
        if (rt) acc += r0p[1]*w12;
        if (dn) { if (lf) acc += rp[-1]*w20; acc += rp[0]*w21; if (rt) acc += rp[1]*w22; }
        op[i] = f2bf(acc);
        s += acc; q += acc*acc;
    }
    for (int off = 32; off > 0; off >>= 1) { s += __shfl_down(s, off); q += __shfl_down(q, off); }
    int wid = tid >> 6, lane = tid & 63;
    if (lane == 0) red[wid] = make_float2(s, q);
    __syncthreads();
    if (tid == 0) {
        for (int i = 1; i < 4; i++) { s += red[i].x; q += red[i].y; }
        part[bc] = make_float2(s, q);   // indexed [b*96+c]
    }
}

// ================= LIF along H: fused gelu(gn(t2)) on load, binary bf16 out =================
__global__ __launch_bounds__(256) void lif_h(const unsigned short* __restrict__ in, unsigned short* __restrict__ out,
        const float2* __restrict__ st_in, const float* __restrict__ gam, const float* __restrict__ bet,
        const float* __restrict__ tau_p, const float* __restrict__ vth_p) {
    int t = blockIdx.x*256 + threadIdx.x;        // B*C*W threads
    int w_ = t % WW;
    int bc = t / WW;
    int b = bc / CC, c = bc - b*CC;
    float2 st = st_in[b];
    float ga = gam[c]*st.y;
    float bb = __builtin_fmaf(-st.x, ga, bet[c]);
    const float tau = *tau_p, vth = *vth_p;
    size_t base = (size_t)bc*HWSZ + w_;
    float u = 0.f, o = 0.f;
    for (int h = 0; h < HH; h++) {
        float xv = gelu_t(__builtin_fmaf(bf2f(in[base + h*WW]), ga, bb));
        u = xv + tau*u*(1.f - o);
        o = (u - vth > 0.f) ? 1.f : 0.f;
        out[base + h*WW] = (u - vth > 0.f) ? (unsigned short)0x3F80 : (unsigned short)0;
    }
}

// ================= LIF along W: LDS-staged, fused gelu(gn), packed bf16 I/O =================
__global__ __launch_bounds__(256) void lif_w(const unsigned short* __restrict__ in, unsigned short* __restrict__ out,
        const float2* __restrict__ st_in, const float* __restrict__ gam, const float* __restrict__ bet,
        const float* __restrict__ tau_p, const float* __restrict__ vth_p) {
    __shared__ float tile[256*57];
    __shared__ float arow[256], brow[256];
    int tid = threadIdx.x;
    // per-row affine coeffs (row = (b,c,h) flattened)
    {
        int R = blockIdx.x*256 + tid;
        int bcr = R / HH;
        int b = bcr / CC, c = bcr - b*CC;
        float2 st = st_in[b];
        float ga = gam[c]*st.y;
        arow[tid] = ga;
        brow[tid] = __builtin_fmaf(-st.x, ga, bet[c]);
    }
    __syncthreads();
    size_t base = (size_t)blockIdx.x * (256*WW);
    for (int i = tid; i < 256*WW; i += 256) {
        int r = i / WW, cix = i - r*WW;
        float v = __builtin_fmaf(bf2f(in[base + i]), arow[r], brow[r]);
        tile[r*57 + cix] = gelu_t(v);
    }
    __syncthreads();
    const float tau = *tau_p, vth = *vth_p;
    float u = 0.f, o = 0.f;
    int off = tid*57;
    for (int w_ = 0; w_ < WW; w_++) {
        float xv = tile[off + w_];
        u = xv + tau*u*(1.f - o);
        o = (u - vth > 0.f) ? 1.f : 0.f;
        tile[off + w_] = o;
    }
    __syncthreads();
    unsigned int* op = (unsigned int*)(out + base);
    for (int i = tid; i < 256*28; i += 256) {    // packed pairs
        int r = i / 28, cp = (i - r*28)*2;
        unsigned int lo = tile[r*57 + cp]     != 0.f ? 0x3F80u : 0u;
        unsigned int hi = tile[r*57 + cp + 1] != 0.f ? 0x3F80u : 0u;
        op[i] = lo | (hi << 16);
    }
}

// ================= dual conv: gelu(conv(xlr,w21)) + gelu(conv(xtd,w22)), stats epilogue =================
__global__ __launch_bounds__(256) void dual_mfma(const unsigned short* __restrict__ xa_g, const unsigned short* __restrict__ xb_g,
        const unsigned short* __restrict__ w1bf, const float* __restrict__ b1,
        const unsigned short* __restrict__ w2bf, const float* __restrict__ b2,
        unsigned short* __restrict__ out, float2* __restrict__ part) {
    __shared__ unsigned short xa[64][NP];
    __shared__ unsigned short xb[64][NP];
    __shared__ float2 red[4];
    int tid = threadIdx.x;
    int b = blockIdx.y;
    int hw0 = blockIdx.x * 64;
    int col = tid & 63;
    const unsigned short* ap = xa_g + (size_t)b*CHW + hw0 + col;
    const unsigned short* bp = xb_g + (size_t)b*CHW + hw0 + col;
    for (int c4 = (tid >> 6)*4; c4 < CC; c4 += 16) {
        unsigned int pa0, pa1, pb0, pb1;
        unsigned short a0 = ap[(size_t)(c4+0)*HWSZ], a1v = ap[(size_t)(c4+1)*HWSZ];
        unsigned short a2 = ap[(size_t)(c4+2)*HWSZ], a3 = ap[(size_t)(c4+3)*HWSZ];
        unsigned short b0v = bp[(size_t)(c4+0)*HWSZ], b1v = bp[(size_t)(c4+1)*HWSZ];
        unsigned short b2v = bp[(size_t)(c4+2)*HWSZ], b3v = bp[(size_t)(c4+3)*HWSZ];
        pa0 = (unsigned int)a0 | ((unsigned int)a1v << 16);
        pa1 = (unsigned int)a2 | ((unsigned int)a3 << 16);
        pb0 = (unsigned int)b0v | ((unsigned int)b1v << 16);
        pb1 = (unsigned int)b2v | ((unsigned int)b3v << 16);
        *reinterpret_cast<uint2*>(&xa[col][c4]) = make_uint2(pa0, pa1);
        *reinterpret_cast<uint2*>(&xb[col][c4]) = make_uint2(pb0, pb1);
    }
    __syncthreads();
    int lane = tid & 63, wid = tid >> 6;
    int ln = lane & 15, k0 = (lane >> 4)*8, n0 = wid*16;
    int wro = ln*CC + k0;
    f32x4 acc1[6], acc2[6];
    #pragma unroll
    for (int t = 0; t < 6; t++) { acc1[t] = (f32x4){0,0,0,0}; acc2[t] = (f32x4){0,0,0,0}; }
    #pragma unroll
    for (int ks = 0; ks < 3; ks++) {
        bf16x8 bfa = ldfrag(&xa[n0+ln][ks*32+k0]);
        bf16x8 bfb = ldfrag(&xb[n0+ln][ks*32+k0]);
        #pragma unroll
        for (int tm = 0; tm < 6; tm++) {
            bf16x8 af1 = ldfrag(w1bf + (size_t)tm*16*CC + ks*32 + wro);
            bf16x8 af2 = ldfrag(w2bf + (size_t)tm*16*CC + ks*32 + wro);
            acc1[tm] = __builtin_amdgcn_mfma_f32_16x16x32_bf16(af1, bfa, acc1[tm], 0, 0, 0);
            acc2[tm] = __builtin_amdgcn_mfma_f32_16x16x32_bf16(af2, bfb, acc2[tm], 0, 0, 0);
        }
    }
    int r0i = (lane >> 4)*4;
    size_t ob = (size_t)b*CHW + hw0 + n0 + ln;
    float s = 0.f, q = 0.f;
    #pragma unroll
    for (int tm = 0; tm < 6; tm++) {
        #pragma unroll
        for (int r = 0; r < 4; r++) {
            int o = tm*16 + r0i + r;
            float v = gelu_t(acc1[tm][r] + b1[o]) + gelu_t(acc2[tm][r] + b2[o]);
            out[ob + (size_t)o*HWSZ] = f2bf(v);
            s += v; q += v*v;
        }
    }
    for (int off = 32; off > 0; off >>= 1) { s += __shfl_down(s, off); q += __shfl_down(q, off); }
    if (lane == 0) red[wid] = make_float2(s, q);
    __syncthreads();
    if (tid == 0) {
        for (int i = 1; i < 4; i++) { s += red[i].x; q += red[i].y; }
        part[b*49 + blockIdx.x] = make_float2(s, q);
    }
}

// ================= fused MLP, batch-paired, in-place on d_out =================
__global__ __launch_bounds__(256) void mlp_mfma(float* __restrict__ xio, const float2* __restrict__ st_in,
        const float* __restrict__ gam, const float* __restrict__ bet,
        const unsigned short* __restrict__ w1bf, const float* __restrict__ b1,
        const unsigned short* __restrict__ w2bf, const float* __restrict__ b2) {
    __shared__ unsigned short xs[128][NP];
    __shared__ unsigned short mc[128][NP];
    __shared__ float gml[CC], btl[CC];
    int tid = threadIdx.x;
    int b0 = blockIdx.y, b1i = b0 + 32;
    int hw0 = blockIdx.x * 64;
    if (tid < CC) { gml[tid] = gam[tid]; btl[tid] = bet[tid]; }
    float2 st0 = st_in[b0], st1 = st_in[b1i];
    __syncthreads();
    int col = tid & 63;
    for (int c4 = (tid >> 6)*4; c4 < CC; c4 += 16) {
        unsigned int pk0[2], pk1[2];
        #pragma unroll
        for (int j = 0; j < 4; j++) {
            int c = c4 + j;
            float r0 = xio[(size_t)b0*CHW + (size_t)c*HWSZ + hw0 + col];
            float r1 = xio[(size_t)b1i*CHW + (size_t)c*HWSZ + hw0 + col];
            float a0 = st0.y * gml[c], b0c = __builtin_fmaf(-st0.x, a0, btl[c]);
            float a1 = st1.y * gml[c], b1c = __builtin_fmaf(-st1.x, a1, btl[c]);
            unsigned short h0 = f2bf(__builtin_fmaf(r0, a0, b0c));
            unsigned short h1 = f2bf(__builtin_fmaf(r1, a1, b1c));
            if (j < 2) { if (j == 0) { pk0[0] = h0; pk1[0] = h1; } else { pk0[0] |= (unsigned int)h0 << 16; pk1[0] |= (unsigned int)h1 << 16; } }
            else       { if (j == 2) { pk0[1] = h0; pk1[1] = h1; } else { pk0[1] |= (unsigned int)h0 << 16; pk1[1] |= (unsigned int)h1 << 16; } }
        }
        *reinterpret_cast<uint2*>(&xs[col][c4])    = make_uint2(pk0[0], pk0[1]);
        *reinterpret_cast<uint2*>(&xs[64+col][c4]) = make_uint2(pk1[0], pk1[1]);
    }
    int lane = tid & 63, wid = tid >> 6;
    int ln = lane & 15, k0 = (lane >> 4)*8, n0 = wid*16;
    int r0i = (lane >> 4)*4;
    f32x4 ao0[6], ao1[6];
    #pragma unroll
    for (int t = 0; t < 6; t++) { ao0[t] = (f32x4){0,0,0,0}; ao1[t] = (f32x4){0,0,0,0}; }
    for (int ch = 0; ch < 4; ch++) {
        __syncthreads();                 // xs ready (ch0); prev-chunk mc reads done (ch>0)
        f32x4 c10[6], c11[6];
        #pragma unroll
        for (int t = 0; t < 6; t++) { c10[t] = (f32x4){0,0,0,0}; c11[t] = (f32x4){0,0,0,0}; }
        #pragma unroll
        for (int ks = 0; ks < 3; ks++) {
            bf16x8 bf0 = ldfrag(&xs[n0+ln][ks*32+k0]);
            bf16x8 bf1 = ldfrag(&xs[64+n0+ln][ks*32+k0]);
            #pragma unroll
            for (int tm = 0; tm < 6; tm++) {
                bf16x8 af = ldfrag(w1bf + (size_t)(ch*CC + tm*16 + ln)*CC + ks*32 + k0);
                c10[tm] = __builtin_amdgcn_mfma_f32_16x16x32_bf16(af, bf0, c10[tm], 0, 0, 0);
                c11[tm] = __builtin_amdgcn_mfma_f32_16x16x32_bf16(af, bf1, c11[tm], 0, 0, 0);
            }
        }
        #pragma unroll
        for (int tm = 0; tm < 6; tm++) {
            int d0 = tm*16 + r0i;
            unsigned short m00 = f2bf(gelu_t(c10[tm][0] + b1[ch*CC + d0 + 0]));
            unsigned short m01 = f2bf(gelu_t(c10[tm][1] + b1[ch*CC + d0 + 1]));
            unsigned short m02 = f2bf(gelu_t(c10[tm][2] + b1[ch*CC + d0 + 2]));
            unsigned short m03 = f2bf(gelu_t(c10[tm][3] + b1[ch*CC + d0 + 3]));
            *reinterpret_cast<uint2*>(&mc[n0+ln][d0]) =
                make_uint2((unsigned int)m00 | ((unsigned int)m01 << 16),
                           (unsigned int)m02 | ((unsigned int)m03 << 16));
            unsigned short m10 = f2bf(gelu_t(c11[tm][0] + b1[ch*CC + d0 + 0]));
            unsigned short m11 = f2bf(gelu_t(c11[tm][1] + b1[ch*CC + d0 + 1]));
            unsigned short m12 = f2bf(gelu_t(c11[tm][2] + b1[ch*CC + d0 + 2]));
            unsigned short m13 = f2bf(gelu_t(c11[tm][3] + b1[ch*CC + d0 + 3]));
            *reinterpret_cast<uint2*>(&mc[64+n0+ln][d0]) =
                make_uint2((unsigned int)m10 | ((unsigned int)m11 << 16),
                           (unsigned int)m12 | ((unsigned int)m13 << 16));
        }
        __syncthreads();                 // mc ready
        #pragma unroll
        for (int ks = 0; ks < 3; ks++) {
            bf16x8 bf0 = ldfrag(&mc[n0+ln][ks*32+k0]);
            bf16x8 bf1 = ldfrag(&mc[64+n0+ln][ks*32+k0]);
            #pragma unroll
            for (int tm = 0; tm < 6; tm++) {
                bf16x8 af = ldfrag(w2bf + (size_t)(tm*16 + ln)*HD + ch*CC + ks*32 + k0);
                ao0[tm] = __builtin_amdgcn_mfma_f32_16x16x32_bf16(af, bf0, ao0[tm], 0, 0, 0);
                ao1[tm] = __builtin_amdgcn_mfma_f32_16x16x32_bf16(af, bf1, ao1[tm], 0, 0, 0);
            }
        }
    }
    size_t ob0 = (size_t)b0*CHW + hw0 + n0 + ln;
    size_t ob1 = (size_t)b1i*CHW + hw0 + n0 + ln;
    #pragma unroll
    for (int tm = 0; tm < 6; tm++) {
        #pragma unroll
        for (int r = 0; r < 4; r++) {
            int o = tm*16 + r0i + r;
            size_t i0 = ob0 + (size_t)o*HWSZ, i1 = ob1 + (size_t)o*HWSZ;
            xio[i0] = xio[i0] + b2[o] + ao0[tm][r];
            xio[i1] = xio[i1] + b2[o] + ao1[tm][r];
        }
    }
}

extern "C" void kernel_launch(void* const* d_in, const int* in_sizes, int n_in,
                              void* d_out, int out_size, void* d_ws, size_t ws_size,
                              hipStream_t stream) {
    (void)in_sizes; (void)n_in; (void)out_size; (void)ws_size;
    const float* x    = (const float*)d_in[0];
    const float* n1g  = (const float*)d_in[1];
    const float* n1b  = (const float*)d_in[2];
    const float* c1w  = (const float*)d_in[3];
    const float* c1b  = (const float*)d_in[4];
    const float* g1g  = (const float*)d_in[5];
    const float* g1b  = (const float*)d_in[6];
    const float* dww  = (const float*)d_in[7];
    const float* dwb  = (const float*)d_in[8];
    const float* g2g  = (const float*)d_in[9];
    const float* g2b  = (const float*)d_in[10];
    const float* tau1 = (const float*)d_in[11];
    const float* vth1 = (const float*)d_in[12];
    const float* tau2 = (const float*)d_in[13];
    const float* vth2 = (const float*)d_in[14];
    const float* c21w = (const float*)d_in[15];
    const float* c21b = (const float*)d_in[16];
    const float* c22w = (const float*)d_in[17];
    const float* c22b = (const float*)d_in[18];
    const float* g3g  = (const float*)d_in[19];
    const float* g3b  = (const float*)d_in[20];
    const float* c3w  = (const float*)d_in[21];
    const float* c3b  = (const float*)d_in[22];
    const float* n2g  = (const float*)d_in[23];
    const float* n2b  = (const float*)d_in[24];
    const float* f1w  = (const float*)d_in[25];
    const float* f1b  = (const float*)d_in[26];
    const float* f2w  = (const float*)d_in[27];
    const float* f2b  = (const float*)d_in[28];
    float* out = (float*)d_out;

    unsigned short* A   = (unsigned short*)d_ws;     // 3 bf16 NTOT buffers
    unsigned short* Bb  = A  + NTOT;
    unsigned short* Cc  = Bb + NTOT;
    unsigned short* WBF = Cc + NTOT;                 // 110592 bf16 weights
    float2* part  = (float2*)(WBF + 110592);         // up to 64*96
    float2* stats = part + 64*96;                    // 5 slots x 64
    float2* s_n1 = stats, * s_g1 = stats+64, * s_g2 = stats+128, * s_g3 = stats+192, * s_n2 = stats+256;

    const unsigned short* Wc1  = WBF;
    const unsigned short* Wc21 = WBF + 9216;
    const unsigned short* Wc22 = WBF + 18432;
    const unsigned short* Wc3  = WBF + 27648;
    const unsigned short* Wf1  = WBF + 36864;
    const unsigned short* Wf2  = WBF + 73728;

    dim3 gStat(S_SPLIT, BB);
    dim3 gPair(HWSZ/64, BB/2);      // (49, 32)
    dim3 gSing(HWSZ/64, BB);        // (49, 64)
    int gLif = (BB*CC*WW)/256;      // 1344

    wconv<<<432,256,0,stream>>>(c1w, c21w, c22w, c3w, f1w, f2w, WBF);
    gn_partial<<<gStat,256,0,stream>>>(x, part);
    gn_final<S_SPLIT><<<1,64,0,stream>>>(part, s_n1);
    convk<false,false><<<gPair,256,0,stream>>>(x, Wc1, c1b, s_n1, n1g, n1b, nullptr, A, part);   // t1 -> A (bf16)
    gn_final<49><<<1,64,0,stream>>>(part, s_g1);
    dw_fused<<<BB*CC,256,0,stream>>>(A, dww, dwb, s_g1, g1g, g1b, Bb, part);                     // t2 -> B
    gn_final<CC><<<1,64,0,stream>>>(part, s_g2);
    lif_h<<<gLif,256,0,stream>>>(Bb, A,  s_g2, g2g, g2b, tau1, vth1);                            // x_lr -> A
    lif_w<<<gLif,256,0,stream>>>(Bb, Cc, s_g2, g2g, g2b, tau2, vth2);                            // x_td -> C
    dual_mfma<<<gSing,256,0,stream>>>(A, Cc, Wc21, c21b, Wc22, c22b, Bb, part);                  // h3 -> B
    gn_final<49><<<1,64,0,stream>>>(part, s_g3);
    convk<true,true><<<gPair,256,0,stream>>>(Bb, Wc3, c3b, s_g3, g3g, g3b, x, out, part);        // x2 -> d_out (f32)
    gn_final<49><<<1,64,0,stream>>>(part, s_n2);
    mlp_mfma<<<gPair,256,0,stream>>>(out, s_n2, n2g, n2b, Wf1, f1b, Wf2, f2b);                   // out = x2 + mlp
}

// Round 5
// 424.166 us; speedup vs baseline: 3.5424x; 1.1923x over previous
//
#include <hip/hip_runtime.h>

#define BB 64
#define CC 96
#define HH 56
#define WW 56
#define HWSZ (HH*WW)          // 3136
#define CHW (CC*HWSZ)         // 301056
#define NTOT ((size_t)BB*CHW) // 19267584
#define S_SPLIT 32
#define CHUNK (CHW/S_SPLIT)   // 9408
#define HD 384
#define NP 104                // LDS row pitch (ushorts): 208B rows, 16B-aligned

typedef float f32x4  __attribute__((ext_vector_type(4)));
typedef short bf16x8 __attribute__((ext_vector_type(8)));

__device__ __forceinline__ unsigned short f2bf(float f) {
    unsigned int u = __float_as_uint(f);
    u = (u + 0x7FFFu + ((u >> 16) & 1u)) >> 16;   // RNE
    return (unsigned short)u;
}
__device__ __forceinline__ float bf2f(unsigned short u) {
    return __uint_as_float(((unsigned int)u) << 16);
}
// tanh-approx GELU: |err| vs exact erf-gelu ~1e-3.
__device__ __forceinline__ float gelu_t(float x) {
    float s = x*x;
    float q = __builtin_fmaf(s, 0.102943f, 2.3021953f) * x;   // 2y*log2e
    float t = exp2f(q);
    float r = __builtin_amdgcn_rcpf(1.0f + t);
    return __builtin_fmaf(-x, r, x);                          // x - x/(1+e^{2y})
}
__device__ __forceinline__ bf16x8 ldfrag(const unsigned short* p) {
    return *reinterpret_cast<const bf16x8*>(p);
}

// ================= weight pre-convert + MFMA-fragment repack (once) =================
// 12 blocks of 96x96, fragment order: W'[blk][tm][ks][lane][j] = W[tm*16+(lane&15)][ks*32+(lane>>4)*8+j]
// blk 0..3: c1w,c21w,c22w,c3w ([96][96]); blk 4..7: f1w chunk ch=blk-4; blk 8..11: f2w chunk ch=blk-8.
__global__ __launch_bounds__(256) void wconv(const float* __restrict__ c1w, const float* __restrict__ c21w,
        const float* __restrict__ c22w, const float* __restrict__ c3w,
        const float* __restrict__ f1w, const float* __restrict__ f2w,
        unsigned short* __restrict__ wbf) {
    int i = blockIdx.x*256 + threadIdx.x;           // 110592 total
    int blk = i / 9216;
    int idx = i - blk*9216;
    int tm   = idx / 1536;
    int rem  = idx - tm*1536;
    int ks   = rem / 512;
    int rem2 = rem - ks*512;
    int lane = rem2 >> 3;
    int j    = rem2 & 7;
    int row = tm*16 + (lane & 15);
    int col = ks*32 + (lane >> 4)*8 + j;
    float v;
    if      (blk == 0) v = c1w [row*CC + col];
    else if (blk == 1) v = c21w[row*CC + col];
    else if (blk == 2) v = c22w[row*CC + col];
    else if (blk == 3) v = c3w [row*CC + col];
    else if (blk <  8) v = f1w[((blk-4)*CC + row)*CC + col];
    else               v = f2w[row*HD + (blk-8)*CC + col];
    wbf[i] = f2bf(v);
}

// ================= GN stats on x (only standalone stats pass) =================
__global__ __launch_bounds__(256) void gn_partial(const float* __restrict__ in, float2* __restrict__ part) {
    int b = blockIdx.y, s = blockIdx.x;
    const float* p = in + (size_t)b*CHW + (size_t)s*CHUNK;
    float sum = 0.f, sq = 0.f;
    for (int i = threadIdx.x; i < CHUNK; i += 256) {
        float v = p[i];
        sum += v; sq += v*v;
    }
    for (int off = 32; off > 0; off >>= 1) {
        sum += __shfl_down(sum, off);
        sq  += __shfl_down(sq,  off);
    }
    __shared__ float2 red[4];
    int wid = threadIdx.x >> 6, lane = threadIdx.x & 63;
    if (lane == 0) red[wid] = make_float2(sum, sq);
    __syncthreads();
    if (threadIdx.x == 0) {
        for (int i = 1; i < 4; i++) { sum += red[i].x; sq += red[i].y; }
        part[b*S_SPLIT + s] = make_float2(sum, sq);
    }
}

template<int NPART>
__global__ void gn_final(const float2* __restrict__ part, float2* __restrict__ stats) {
    int b = threadIdx.x;
    if (b >= BB) return;
    float s = 0.f, q = 0.f;
    for (int i = 0; i < NPART; i++) { float2 v = part[b*NPART + i]; s += v.x; q += v.y; }
    float mean = s / (float)CHW;
    float var  = q / (float)CHW - mean*mean;
    stats[b] = make_float2(mean, rsqrtf(var + 1e-5f));
}

// ================= batch-paired 1x1 conv with pre-norm + stats epilogue =================
template<bool IN_BF, bool OUT_RES>
__global__ __launch_bounds__(256) void convk(const void* __restrict__ in_,
        const unsigned short* __restrict__ wbf, const float* __restrict__ bias,
        const float2* __restrict__ st_in, const float* __restrict__ gam, const float* __restrict__ bet,
        const float* __restrict__ res, void* __restrict__ out_, float2* __restrict__ part) {
    __shared__ unsigned short xs[128][NP];
    __shared__ float gml[CC], btl[CC];
    __shared__ float2 red[8];
    int tid = threadIdx.x;
    int b0 = blockIdx.y, b1 = b0 + 32;
    int hw0 = blockIdx.x * 64;
    if (tid < CC) { gml[tid] = gam[tid]; btl[tid] = bet[tid]; }
    float2 st0 = st_in[b0], st1 = st_in[b1];
    __syncthreads();
    int col = tid & 63;
    for (int c4 = (tid >> 6)*4; c4 < CC; c4 += 16) {
        unsigned int pk0[2], pk1[2];
        #pragma unroll
        for (int j = 0; j < 4; j++) {
            int c = c4 + j;
            size_t off0 = (size_t)b0*CHW + (size_t)c*HWSZ + hw0 + col;
            size_t off1 = (size_t)b1*CHW + (size_t)c*HWSZ + hw0 + col;
            float r0 = IN_BF ? bf2f(((const unsigned short*)in_)[off0]) : ((const float*)in_)[off0];
            float r1 = IN_BF ? bf2f(((const unsigned short*)in_)[off1]) : ((const float*)in_)[off1];
            float a0 = st0.y * gml[c], b0c = __builtin_fmaf(-st0.x, a0, btl[c]);
            float a1 = st1.y * gml[c], b1c = __builtin_fmaf(-st1.x, a1, btl[c]);
            unsigned short h0 = f2bf(__builtin_fmaf(r0, a0, b0c));
            unsigned short h1 = f2bf(__builtin_fmaf(r1, a1, b1c));
            if (j < 2) { if (j == 0) { pk0[0] = h0; pk1[0] = h1; } else { pk0[0] |= (unsigned int)h0 << 16; pk1[0] |= (unsigned int)h1 << 16; } }
            else       { if (j == 2) { pk0[1] = h0; pk1[1] = h1; } else { pk0[1] |= (unsigned int)h0 << 16; pk1[1] |= (unsigned int)h1 << 16; } }
        }
        *reinterpret_cast<uint2*>(&xs[col][c4])      = make_uint2(pk0[0], pk0[1]);
        *reinterpret_cast<uint2*>(&xs[64+col][c4])   = make_uint2(pk1[0], pk1[1]);
    }
    __syncthreads();
    int lane = tid & 63, wid = tid >> 6;
    int ln = lane & 15, k0 = (lane >> 4)*8, n0 = wid*16;
    const unsigned short* wl = wbf + lane*8;
    f32x4 a0[6], a1[6];
    #pragma unroll
    for (int t = 0; t < 6; t++) { a0[t] = (f32x4){0,0,0,0}; a1[t] = (f32x4){0,0,0,0}; }
    #pragma unroll
    for (int ks = 0; ks < 3; ks++) {
        bf16x8 bf0 = ldfrag(&xs[n0+ln][ks*32+k0]);
        bf16x8 bf1 = ldfrag(&xs[64+n0+ln][ks*32+k0]);
        #pragma unroll
        for (int tm = 0; tm < 6; tm++) {
            bf16x8 af = ldfrag(wl + (tm*3+ks)*512);
            a0[tm] = __builtin_amdgcn_mfma_f32_16x16x32_bf16(af, bf0, a0[tm], 0, 0, 0);
            a1[tm] = __builtin_amdgcn_mfma_f32_16x16x32_bf16(af, bf1, a1[tm], 0, 0, 0);
        }
    }
    int r0i = (lane >> 4)*4;
    size_t ob0 = (size_t)b0*CHW + hw0 + n0 + ln;
    size_t ob1 = (size_t)b1*CHW + hw0 + n0 + ln;
    float s0 = 0.f, q0 = 0.f, s1 = 0.f, q1 = 0.f;
    #pragma unroll
    for (int tm = 0; tm < 6; tm++) {
        #pragma unroll
        for (int r = 0; r < 4; r++) {
            int o = tm*16 + r0i + r;
            size_t i0 = ob0 + (size_t)o*HWSZ, i1 = ob1 + (size_t)o*HWSZ;
            float v0 = a0[tm][r] + bias[o];
            float v1 = a1[tm][r] + bias[o];
            if (OUT_RES) { v0 += res[i0]; v1 += res[i1];
                           ((float*)out_)[i0] = v0; ((float*)out_)[i1] = v1; }
            else         { ((unsigned short*)out_)[i0] = f2bf(v0); ((unsigned short*)out_)[i1] = f2bf(v1); }
            s0 += v0; q0 += v0*v0; s1 += v1; q1 += v1*v1;
        }
    }
    for (int off = 32; off > 0; off >>= 1) {
        s0 += __shfl_down(s0, off); q0 += __shfl_down(q0, off);
        s1 += __shfl_down(s1, off); q1 += __shfl_down(q1, off);
    }
    if (lane == 0) { red[wid] = make_float2(s0, q0); red[4+wid] = make_float2(s1, q1); }
    __syncthreads();
    if (tid == 0) {
        float S0=0,Q0=0,S1=0,Q1=0;
        for (int i = 0; i < 4; i++) { S0 += red[i].x; Q0 += red[i].y; S1 += red[4+i].x; Q1 += red[4+i].y; }
        part[b0*49 + blockIdx.x] = make_float2(S0, Q0);
        part[b1*49 + blockIdx.x] = make_float2(S1, Q1);
    }
}

// ================= depthwise 3x3: fused gelu(gn(t1)) on stage-in, stats epilogue =================
__global__ __launch_bounds__(256) void dw_fused(const unsigned short* __restrict__ t1,
        const float* __restrict__ dww, const float* __restrict__ dwb,
        const float2* __restrict__ st_in, const float* __restrict__ gam, const float* __restrict__ bet,
        unsigned short* __restrict__ t2, float2* __restrict__ part) {
    __shared__ float tile[HH*57];
    __shared__ float2 red[4];
    int bc = blockIdx.x;
    int b = bc / CC, c = bc - b*CC;
    int tid = threadIdx.x;
    float2 st = st_in[b];
    float ga = gam[c]*st.y;
    float bb = __builtin_fmaf(-st.x, ga, bet[c]);
    const unsigned short* ip = t1 + (size_t)bc*HWSZ;
    for (int i = tid; i < HWSZ; i += 256) {
        float v = __builtin_fmaf(bf2f(ip[i]), ga, bb);
        tile[(i/WW)*57 + (i%WW)] = gelu_t(v);
    }
    __syncthreads();
    float w00=dww[c*9+0],w01=dww[c*9+1],w02=dww[c*9+2],
          w10=dww[c*9+3],w11=dww[c*9+4],w12=dww[c*9+5],
          w20=dww[c*9+6],w21=dww[c*9+7],w22=dww[c*9+8];
    float bs = dwb[c];
    unsigned short* op = t2 + (size_t)bc*HWSZ;
    float s = 0.f, q = 0.f;
    for (int i = tid; i < HWSZ; i += 256) {
        int h = i/WW, w_ = i - h*WW;
        float acc = bs;
        int up = h > 0, dn = h < HH-1, lf = w_ > 0, rt = w_ < WW-1;
        const float* rm = &tile[(h-1)*57 + w_];
        const float* r0p = &tile[h*57 + w_];
        const float* rp = &tile[(h+1)*57 + w_];
        if (up) { if (lf) acc += rm[-1]*w00; acc += rm[0]*w01; if (rt) acc += rm[1]*w02; }
        if (lf) acc += r0p[-1]*w10;
        acc += r0p[0]*w11;
        if (rt) acc += r0p[1]*w12;
        if (dn) { if (lf) acc += rp[-1]*w20; acc += rp[0]*w21; if (rt) acc += rp[1]*w22; }
        op[i] = f2bf(acc);
        s += acc; q += acc*acc;
    }
    for (int off = 32; off > 0; off >>= 1) { s += __shfl_down(s, off); q += __shfl_down(q, off); }
    int wid = tid >> 6, lane = tid & 63;
    if (lane == 0) red[wid] = make_float2(s, q);
    __syncthreads();
    if (tid == 0) {
        for (int i = 1; i < 4; i++) { s += red[i].x; q += red[i].y; }
        part[bc] = make_float2(s, q);   // indexed [b*96+c]
    }
}

// ================= LIF along H: fused gelu(gn(t2)) on load, binary bf16 out =================
__global__ __launch_bounds__(256) void lif_h(const unsigned short* __restrict__ in, unsigned short* __restrict__ out,
        const float2* __restrict__ st_in, const float* __restrict__ gam, const float* __restrict__ bet,
        const float* __restrict__ tau_p, const float* __restrict__ vth_p) {
    int t = blockIdx.x*256 + threadIdx.x;        // B*C*W threads
    int w_ = t % WW;
    int bc = t / WW;
    int b = bc / CC, c = bc - b*CC;
    float2 st = st_in[b];
    float ga = gam[c]*st.y;
    float bb = __builtin_fmaf(-st.x, ga, bet[c]);
    const float tau = *tau_p, vth = *vth_p;
    size_t base = (size_t)bc*HWSZ + w_;
    float u = 0.f, o = 0.f;
    for (int h = 0; h < HH; h++) {
        float xv = gelu_t(__builtin_fmaf(bf2f(in[base + h*WW]), ga, bb));
        u = xv + tau*u*(1.f - o);
        o = (u - vth > 0.f) ? 1.f : 0.f;
        out[base + h*WW] = (u - vth > 0.f) ? (unsigned short)0x3F80 : (unsigned short)0;
    }
}

// ================= LIF along W: LDS-staged, fused gelu(gn), packed bf16 I/O =================
__global__ __launch_bounds__(256) void lif_w(const unsigned short* __restrict__ in, unsigned short* __restrict__ out,
        const float2* __restrict__ st_in, const float* __restrict__ gam, const float* __restrict__ bet,
        const float* __restrict__ tau_p, const float* __restrict__ vth_p) {
    __shared__ float tile[256*57];
    __shared__ float arow[256], brow[256];
    int tid = threadIdx.x;
    {
        int R = blockIdx.x*256 + tid;
        int bcr = R / HH;
        int b = bcr / CC, c = bcr - b*CC;
        float2 st = st_in[b];
        float ga = gam[c]*st.y;
        arow[tid] = ga;
        brow[tid] = __builtin_fmaf(-st.x, ga, bet[c]);
    }
    __syncthreads();
    size_t base = (size_t)blockIdx.x * (256*WW);
    for (int i = tid; i < 256*WW; i += 256) {
        int r = i / WW, cix = i - r*WW;
        float v = __builtin_fmaf(bf2f(in[base + i]), arow[r], brow[r]);
        tile[r*57 + cix] = gelu_t(v);
    }
    __syncthreads();
    const float tau = *tau_p, vth = *vth_p;
    float u = 0.f, o = 0.f;
    int off = tid*57;
    for (int w_ = 0; w_ < WW; w_++) {
        float xv = tile[off + w_];
        u = xv + tau*u*(1.f - o);
        o = (u - vth > 0.f) ? 1.f : 0.f;
        tile[off + w_] = o;
    }
    __syncthreads();
    unsigned int* op = (unsigned int*)(out + base);
    for (int i = tid; i < 256*28; i += 256) {    // packed pairs
        int r = i / 28, cp = (i - r*28)*2;
        unsigned int lo = tile[r*57 + cp]     != 0.f ? 0x3F80u : 0u;
        unsigned int hi = tile[r*57 + cp + 1] != 0.f ? 0x3F80u : 0u;
        op[i] = lo | (hi << 16);
    }
}

// ================= dual conv: gelu(conv(xlr,w21)) + gelu(conv(xtd,w22)), stats epilogue =================
__global__ __launch_bounds__(256) void dual_mfma(const unsigned short* __restrict__ xa_g, const unsigned short* __restrict__ xb_g,
        const unsigned short* __restrict__ w1bf, const float* __restrict__ b1,
        const unsigned short* __restrict__ w2bf, const float* __restrict__ b2,
        unsigned short* __restrict__ out, float2* __restrict__ part) {
    __shared__ unsigned short xa[64][NP];
    __shared__ unsigned short xb[64][NP];
    __shared__ float2 red[4];
    int tid = threadIdx.x;
    int b = blockIdx.y;
    int hw0 = blockIdx.x * 64;
    int col = tid & 63;
    const unsigned short* ap = xa_g + (size_t)b*CHW + hw0 + col;
    const unsigned short* bp = xb_g + (size_t)b*CHW + hw0 + col;
    for (int c4 = (tid >> 6)*4; c4 < CC; c4 += 16) {
        unsigned int pa0, pa1, pb0, pb1;
        unsigned short a0 = ap[(size_t)(c4+0)*HWSZ], a1v = ap[(size_t)(c4+1)*HWSZ];
        unsigned short a2 = ap[(size_t)(c4+2)*HWSZ], a3 = ap[(size_t)(c4+3)*HWSZ];
        unsigned short b0v = bp[(size_t)(c4+0)*HWSZ], b1v = bp[(size_t)(c4+1)*HWSZ];
        unsigned short b2v = bp[(size_t)(c4+2)*HWSZ], b3v = bp[(size_t)(c4+3)*HWSZ];
        pa0 = (unsigned int)a0 | ((unsigned int)a1v << 16);
        pa1 = (unsigned int)a2 | ((unsigned int)a3 << 16);
        pb0 = (unsigned int)b0v | ((unsigned int)b1v << 16);
        pb1 = (unsigned int)b2v | ((unsigned int)b3v << 16);
        *reinterpret_cast<uint2*>(&xa[col][c4]) = make_uint2(pa0, pa1);
        *reinterpret_cast<uint2*>(&xb[col][c4]) = make_uint2(pb0, pb1);
    }
    __syncthreads();
    int lane = tid & 63, wid = tid >> 6;
    int ln = lane & 15, k0 = (lane >> 4)*8, n0 = wid*16;
    const unsigned short* wl1 = w1bf + lane*8;
    const unsigned short* wl2 = w2bf + lane*8;
    f32x4 acc1[6], acc2[6];
    #pragma unroll
    for (int t = 0; t < 6; t++) { acc1[t] = (f32x4){0,0,0,0}; acc2[t] = (f32x4){0,0,0,0}; }
    #pragma unroll
    for (int ks = 0; ks < 3; ks++) {
        bf16x8 bfa = ldfrag(&xa[n0+ln][ks*32+k0]);
        bf16x8 bfb = ldfrag(&xb[n0+ln][ks*32+k0]);
        #pragma unroll
        for (int tm = 0; tm < 6; tm++) {
            bf16x8 af1 = ldfrag(wl1 + (tm*3+ks)*512);
            bf16x8 af2 = ldfrag(wl2 + (tm*3+ks)*512);
            acc1[tm] = __builtin_amdgcn_mfma_f32_16x16x32_bf16(af1, bfa, acc1[tm], 0, 0, 0);
            acc2[tm] = __builtin_amdgcn_mfma_f32_16x16x32_bf16(af2, bfb, acc2[tm], 0, 0, 0);
        }
    }
    int r0i = (lane >> 4)*4;
    size_t ob = (size_t)b*CHW + hw0 + n0 + ln;
    float s = 0.f, q = 0.f;
    #pragma unroll
    for (int tm = 0; tm < 6; tm++) {
        #pragma unroll
        for (int r = 0; r < 4; r++) {
            int o = tm*16 + r0i + r;
            float v = gelu_t(acc1[tm][r] + b1[o]) + gelu_t(acc2[tm][r] + b2[o]);
            out[ob + (size_t)o*HWSZ] = f2bf(v);
            s += v; q += v*v;
        }
    }
    for (int off = 32; off > 0; off >>= 1) { s += __shfl_down(s, off); q += __shfl_down(q, off); }
    if (lane == 0) red[wid] = make_float2(s, q);
    __syncthreads();
    if (tid == 0) {
        for (int i = 1; i < 4; i++) { s += red[i].x; q += red[i].y; }
        part[b*49 + blockIdx.x] = make_float2(s, q);
    }
}

// ================= fused MLP, 512 threads, batch-paired, in-place on d_out =================
// wave w (0..7): batch half bs=w>>2, col-quarter n0=(w&3)*16.
// After xs staging barrier, waves are fully independent: xs is read-only and each
// wave's mc rows (xrow set) are written/read only by itself -> NO in-loop barriers.
__global__ __launch_bounds__(512, 4) void mlp_mfma(float* __restrict__ xio, const float2* __restrict__ st_in,
        const float* __restrict__ gam, const float* __restrict__ bet,
        const unsigned short* __restrict__ wbf, const float* __restrict__ b1, const float* __restrict__ b2) {
    __shared__ unsigned short xs[128][NP];
    __shared__ unsigned short mc[128][NP];
    __shared__ float gml[CC], btl[CC];
    int tid = threadIdx.x;
    int b0 = blockIdx.y, b1i = b0 + 32;
    int hw0 = blockIdx.x * 64;
    if (tid < CC) { gml[tid] = gam[tid]; btl[tid] = bet[tid]; }
    float2 st0 = st_in[b0], st1 = st_in[b1i];
    __syncthreads();
    // stage: col = tid&63, bsel = (tid>>6)&1, cgrp = tid>>7
    {
        int col = tid & 63;
        int bsel = (tid >> 6) & 1;
        float2 st = bsel ? st1 : st0;
        size_t base = (size_t)(bsel ? b1i : b0)*CHW + hw0 + col;
        for (int c4 = (tid >> 7)*4; c4 < CC; c4 += 16) {
            unsigned int pk[2];
            #pragma unroll
            for (int j = 0; j < 4; j++) {
                int c = c4 + j;
                float rv = xio[base + (size_t)c*HWSZ];
                float a = st.y * gml[c];
                float bc = __builtin_fmaf(-st.x, a, btl[c]);
                unsigned short h = f2bf(__builtin_fmaf(rv, a, bc));
                if (j < 2) { if (j == 0) pk[0] = h; else pk[0] |= (unsigned int)h << 16; }
                else       { if (j == 2) pk[1] = h; else pk[1] |= (unsigned int)h << 16; }
            }
            *reinterpret_cast<uint2*>(&xs[bsel*64 + col][c4]) = make_uint2(pk[0], pk[1]);
        }
    }
    __syncthreads();                   // xs fully staged (cross-wave) -- THE fix
    int lane = tid & 63, wv = tid >> 6;
    int bs = wv >> 2;                 // batch half
    int n0 = (wv & 3)*16;             // col quarter
    int ln = lane & 15, k0 = (lane >> 4)*8;
    int r0i = (lane >> 4)*4;
    int xrow = bs*64 + n0 + ln;
    f32x4 ao[6];
    #pragma unroll
    for (int t = 0; t < 6; t++) ao[t] = (f32x4){0,0,0,0};
    for (int ch = 0; ch < 4; ch++) {
        const unsigned short* w1l = wbf + (4+ch)*9216 + lane*8;
        const unsigned short* w2l = wbf + (8+ch)*9216 + lane*8;
        f32x4 c1[6];
        #pragma unroll
        for (int t = 0; t < 6; t++) c1[t] = (f32x4){0,0,0,0};
        #pragma unroll
        for (int ks = 0; ks < 3; ks++) {
            bf16x8 bf = ldfrag(&xs[xrow][ks*32+k0]);
            #pragma unroll
            for (int tm = 0; tm < 6; tm++) {
                bf16x8 af = ldfrag(w1l + (tm*3+ks)*512);
                c1[tm] = __builtin_amdgcn_mfma_f32_16x16x32_bf16(af, bf, c1[tm], 0, 0, 0);
            }
        }
        // mc rows are wave-private (row set {bs*64+n0+ln}); lgkmcnt orders write->read
        #pragma unroll
        for (int tm = 0; tm < 6; tm++) {
            int d0 = tm*16 + r0i;
            unsigned short m0 = f2bf(gelu_t(c1[tm][0] + b1[ch*CC + d0 + 0]));
            unsigned short m1 = f2bf(gelu_t(c1[tm][1] + b1[ch*CC + d0 + 1]));
            unsigned short m2 = f2bf(gelu_t(c1[tm][2] + b1[ch*CC + d0 + 2]));
            unsigned short m3 = f2bf(gelu_t(c1[tm][3] + b1[ch*CC + d0 + 3]));
            *reinterpret_cast<uint2*>(&mc[xrow][d0]) =
                make_uint2((unsigned int)m0 | ((unsigned int)m1 << 16),
                           (unsigned int)m2 | ((unsigned int)m3 << 16));
        }
        #pragma unroll
        for (int ks = 0; ks < 3; ks++) {
            bf16x8 bf = ldfrag(&mc[xrow][ks*32+k0]);
            #pragma unroll
            for (int tm = 0; tm < 6; tm++) {
                bf16x8 af = ldfrag(w2l + (tm*3+ks)*512);
                ao[tm] = __builtin_amdgcn_mfma_f32_16x16x32_bf16(af, bf, ao[tm], 0, 0, 0);
            }
        }
    }
    size_t ob = (size_t)(bs ? b1i : b0)*CHW + hw0 + n0 + ln;
    #pragma unroll
    for (int tm = 0; tm < 6; tm++) {
        #pragma unroll
        for (int r = 0; r < 4; r++) {
            int o = tm*16 + r0i + r;
            size_t i0 = ob + (size_t)o*HWSZ;
            xio[i0] = xio[i0] + b2[o] + ao[tm][r];
        }
    }
}

extern "C" void kernel_launch(void* const* d_in, const int* in_sizes, int n_in,
                              void* d_out, int out_size, void* d_ws, size_t ws_size,
                              hipStream_t stream) {
    (void)in_sizes; (void)n_in; (void)out_size; (void)ws_size;
    const float* x    = (const float*)d_in[0];
    const float* n1g  = (const float*)d_in[1];
    const float* n1b  = (const float*)d_in[2];
    const float* c1w  = (const float*)d_in[3];
    const float* c1b  = (const float*)d_in[4];
    const float* g1g  = (const float*)d_in[5];
    const float* g1b  = (const float*)d_in[6];
    const float* dww  = (const float*)d_in[7];
    const float* dwb  = (const float*)d_in[8];
    const float* g2g  = (const float*)d_in[9];
    const float* g2b  = (const float*)d_in[10];
    const float* tau1 = (const float*)d_in[11];
    const float* vth1 = (const float*)d_in[12];
    const float* tau2 = (const float*)d_in[13];
    const float* vth2 = (const float*)d_in[14];
    const float* c21w = (const float*)d_in[15];
    const float* c21b = (const float*)d_in[16];
    const float* c22w = (const float*)d_in[17];
    const float* c22b = (const float*)d_in[18];
    const float* g3g  = (const float*)d_in[19];
    const float* g3b  = (const float*)d_in[20];
    const float* c3w  = (const float*)d_in[21];
    const float* c3b  = (const float*)d_in[22];
    const float* n2g  = (const float*)d_in[23];
    const float* n2b  = (const float*)d_in[24];
    const float* f1w  = (const float*)d_in[25];
    const float* f1b  = (const float*)d_in[26];
    const float* f2w  = (const float*)d_in[27];
    const float* f2b  = (const float*)d_in[28];
    float* out = (float*)d_out;

    unsigned short* A   = (unsigned short*)d_ws;     // 3 bf16 NTOT buffers
    unsigned short* Bb  = A  + NTOT;
    unsigned short* Cc  = Bb + NTOT;
    unsigned short* WBF = Cc + NTOT;                 // 110592 bf16 weights (fragment-repacked)
    float2* part  = (float2*)(WBF + 110592);
    float2* stats = part + 64*96;
    float2* s_n1 = stats, * s_g1 = stats+64, * s_g2 = stats+128, * s_g3 = stats+192, * s_n2 = stats+256;

    const unsigned short* Wc1  = WBF;
    const unsigned short* Wc21 = WBF + 9216;
    const unsigned short* Wc22 = WBF + 18432;
    const unsigned short* Wc3  = WBF + 27648;

    dim3 gStat(S_SPLIT, BB);
    dim3 gPair(HWSZ/64, BB/2);      // (49, 32)
    dim3 gSing(HWSZ/64, BB);        // (49, 64)
    int gLif = (BB*CC*WW)/256;      // 1344

    wconv<<<432,256,0,stream>>>(c1w, c21w, c22w, c3w, f1w, f2w, WBF);
    gn_partial<<<gStat,256,0,stream>>>(x, part);
    gn_final<S_SPLIT><<<1,64,0,stream>>>(part, s_n1);
    convk<false,false><<<gPair,256,0,stream>>>(x, Wc1, c1b, s_n1, n1g, n1b, nullptr, A, part);   // t1 -> A (bf16)
    gn_final<49><<<1,64,0,stream>>>(part, s_g1);
    dw_fused<<<BB*CC,256,0,stream>>>(A, dww, dwb, s_g1, g1g, g1b, Bb, part);                     // t2 -> B
    gn_final<CC><<<1,64,0,stream>>>(part, s_g2);
    lif_h<<<gLif,256,0,stream>>>(Bb, A,  s_g2, g2g, g2b, tau1, vth1);                            // x_lr -> A
    lif_w<<<gLif,256,0,stream>>>(Bb, Cc, s_g2, g2g, g2b, tau2, vth2);                            // x_td -> C
    dual_mfma<<<gSing,256,0,stream>>>(A, Cc, Wc21, c21b, Wc22, c22b, Bb, part);                  // h3 -> B
    gn_final<49><<<1,64,0,stream>>>(part, s_g3);
    convk<true,true><<<gPair,256,0,stream>>>(Bb, Wc3, c3b, s_g3, g3g, g3b, x, out, part);        // x2 -> d_out (f32)
    gn_final<49><<<1,64,0,stream>>>(part, s_n2);
    mlp_mfma<<<gPair,512,0,stream>>>(out, s_n2, n2g, n2b, WBF, f1b, f2b);                        // out = x2 + mlp
}

// Round 6
// 319.830 us; speedup vs baseline: 4.6980x; 1.3262x over previous
//
#include <hip/hip_runtime.h>

#define BB 64
#define CC 96
#define HH 56
#define WW 56
#define HWSZ (HH*WW)          // 3136
#define CHW (CC*HWSZ)         // 301056
#define NTOT ((size_t)BB*CHW) // 19267584
#define S_SPLIT 32
#define CHUNK (CHW/S_SPLIT)   // 9408
#define HD 384
#define NP 104                // LDS row pitch (ushorts): 208B rows, 16B-aligned

typedef float f32x4  __attribute__((ext_vector_type(4)));
typedef short bf16x8 __attribute__((ext_vector_type(8)));
typedef unsigned short u16x4 __attribute__((ext_vector_type(4)));

__device__ __forceinline__ unsigned short f2bf(float f) {
    unsigned int u = __float_as_uint(f);
    u = (u + 0x7FFFu + ((u >> 16) & 1u)) >> 16;   // RNE
    return (unsigned short)u;
}
__device__ __forceinline__ float bf2f(unsigned short u) {
    return __uint_as_float(((unsigned int)u) << 16);
}
// tanh-approx GELU: |err| vs exact erf-gelu ~1e-3.
__device__ __forceinline__ float gelu_t(float x) {
    float s = x*x;
    float q = __builtin_fmaf(s, 0.102943f, 2.3021953f) * x;   // 2y*log2e
    float t = exp2f(q);
    float r = __builtin_amdgcn_rcpf(1.0f + t);
    return __builtin_fmaf(-x, r, x);                          // x - x/(1+e^{2y})
}
__device__ __forceinline__ bf16x8 ldfrag(const unsigned short* p) {
    return *reinterpret_cast<const bf16x8*>(p);
}

// ================= weight pre-convert + MFMA-fragment repack (once) =================
// 12 blocks of 96x96, fragment order: W'[blk][tm][ks][lane][j] = W[tm*16+(lane&15)][ks*32+(lane>>4)*8+j]
// blk 0..3: c1w,c21w,c22w,c3w; blk 4..7: f1w chunk ch=blk-4; blk 8..11: f2w chunk ch=blk-8.
__global__ __launch_bounds__(256) void wconv(const float* __restrict__ c1w, const float* __restrict__ c21w,
        const float* __restrict__ c22w, const float* __restrict__ c3w,
        const float* __restrict__ f1w, const float* __restrict__ f2w,
        unsigned short* __restrict__ wbf) {
    int i = blockIdx.x*256 + threadIdx.x;           // 110592 total
    int blk = i / 9216;
    int idx = i - blk*9216;
    int tm   = idx / 1536;
    int rem  = idx - tm*1536;
    int ks   = rem / 512;
    int rem2 = rem - ks*512;
    int lane = rem2 >> 3;
    int j    = rem2 & 7;
    int row = tm*16 + (lane & 15);
    int col = ks*32 + (lane >> 4)*8 + j;
    float v;
    if      (blk == 0) v = c1w [row*CC + col];
    else if (blk == 1) v = c21w[row*CC + col];
    else if (blk == 2) v = c22w[row*CC + col];
    else if (blk == 3) v = c3w [row*CC + col];
    else if (blk <  8) v = f1w[((blk-4)*CC + row)*CC + col];
    else               v = f2w[row*HD + (blk-8)*CC + col];
    wbf[i] = f2bf(v);
}

// ================= GN stats on x (only standalone stats pass) =================
__global__ __launch_bounds__(256) void gn_partial(const float* __restrict__ in, float2* __restrict__ part) {
    int b = blockIdx.y, s = blockIdx.x;
    const float* p = in + (size_t)b*CHW + (size_t)s*CHUNK;
    float sum = 0.f, sq = 0.f;
    for (int i = threadIdx.x; i < CHUNK; i += 256) {
        float v = p[i];
        sum += v; sq += v*v;
    }
    for (int off = 32; off > 0; off >>= 1) {
        sum += __shfl_down(sum, off);
        sq  += __shfl_down(sq,  off);
    }
    __shared__ float2 red[4];
    int wid = threadIdx.x >> 6, lane = threadIdx.x & 63;
    if (lane == 0) red[wid] = make_float2(sum, sq);
    __syncthreads();
    if (threadIdx.x == 0) {
        for (int i = 1; i < 4; i++) { sum += red[i].x; sq += red[i].y; }
        part[b*S_SPLIT + s] = make_float2(sum, sq);
    }
}

template<int NPART>
__global__ void gn_final(const float2* __restrict__ part, float2* __restrict__ stats) {
    int b = threadIdx.x;
    if (b >= BB) return;
    float s = 0.f, q = 0.f;
    for (int i = 0; i < NPART; i++) { float2 v = part[b*NPART + i]; s += v.x; q += v.y; }
    float mean = s / (float)CHW;
    float var  = q / (float)CHW - mean*mean;
    stats[b] = make_float2(mean, rsqrtf(var + 1e-5f));
}

// ================= batch-paired 1x1 conv with pre-norm + stats epilogue =================
template<bool IN_BF, bool OUT_RES>
__global__ __launch_bounds__(256) void convk(const void* __restrict__ in_,
        const unsigned short* __restrict__ wbf, const float* __restrict__ bias,
        const float2* __restrict__ st_in, const float* __restrict__ gam, const float* __restrict__ bet,
        const float* __restrict__ res, void* __restrict__ out_, float2* __restrict__ part) {
    __shared__ unsigned short xs[128][NP];
    __shared__ float gml[CC], btl[CC];
    __shared__ float2 red[8];
    int tid = threadIdx.x;
    int b0 = blockIdx.y, b1 = b0 + 32;
    int hw0 = blockIdx.x * 64;
    if (tid < CC) { gml[tid] = gam[tid]; btl[tid] = bet[tid]; }
    float2 st0 = st_in[b0], st1 = st_in[b1];
    __syncthreads();
    int col = tid & 63;
    for (int c4 = (tid >> 6)*4; c4 < CC; c4 += 16) {
        unsigned int pk0[2], pk1[2];
        #pragma unroll
        for (int j = 0; j < 4; j++) {
            int c = c4 + j;
            size_t off0 = (size_t)b0*CHW + (size_t)c*HWSZ + hw0 + col;
            size_t off1 = (size_t)b1*CHW + (size_t)c*HWSZ + hw0 + col;
            float r0 = IN_BF ? bf2f(((const unsigned short*)in_)[off0]) : ((const float*)in_)[off0];
            float r1 = IN_BF ? bf2f(((const unsigned short*)in_)[off1]) : ((const float*)in_)[off1];
            float a0 = st0.y * gml[c], b0c = __builtin_fmaf(-st0.x, a0, btl[c]);
            float a1 = st1.y * gml[c], b1c = __builtin_fmaf(-st1.x, a1, btl[c]);
            unsigned short h0 = f2bf(__builtin_fmaf(r0, a0, b0c));
            unsigned short h1 = f2bf(__builtin_fmaf(r1, a1, b1c));
            if (j < 2) { if (j == 0) { pk0[0] = h0; pk1[0] = h1; } else { pk0[0] |= (unsigned int)h0 << 16; pk1[0] |= (unsigned int)h1 << 16; } }
            else       { if (j == 2) { pk0[1] = h0; pk1[1] = h1; } else { pk0[1] |= (unsigned int)h0 << 16; pk1[1] |= (unsigned int)h1 << 16; } }
        }
        *reinterpret_cast<uint2*>(&xs[col][c4])      = make_uint2(pk0[0], pk0[1]);
        *reinterpret_cast<uint2*>(&xs[64+col][c4])   = make_uint2(pk1[0], pk1[1]);
    }
    __syncthreads();
    int lane = tid & 63, wid = tid >> 6;
    int ln = lane & 15, k0 = (lane >> 4)*8, n0 = wid*16;
    const unsigned short* wl = wbf + lane*8;
    f32x4 a0[6], a1[6];
    #pragma unroll
    for (int t = 0; t < 6; t++) { a0[t] = (f32x4){0,0,0,0}; a1[t] = (f32x4){0,0,0,0}; }
    #pragma unroll
    for (int ks = 0; ks < 3; ks++) {
        bf16x8 bf0 = ldfrag(&xs[n0+ln][ks*32+k0]);
        bf16x8 bf1 = ldfrag(&xs[64+n0+ln][ks*32+k0]);
        #pragma unroll
        for (int tm = 0; tm < 6; tm++) {
            bf16x8 af = ldfrag(wl + (tm*3+ks)*512);
            a0[tm] = __builtin_amdgcn_mfma_f32_16x16x32_bf16(af, bf0, a0[tm], 0, 0, 0);
            a1[tm] = __builtin_amdgcn_mfma_f32_16x16x32_bf16(af, bf1, a1[tm], 0, 0, 0);
        }
    }
    int r0i = (lane >> 4)*4;
    size_t ob0 = (size_t)b0*CHW + hw0 + n0 + ln;
    size_t ob1 = (size_t)b1*CHW + hw0 + n0 + ln;
    float s0 = 0.f, q0 = 0.f, s1 = 0.f, q1 = 0.f;
    #pragma unroll
    for (int tm = 0; tm < 6; tm++) {
        #pragma unroll
        for (int r = 0; r < 4; r++) {
            int o = tm*16 + r0i + r;
            size_t i0 = ob0 + (size_t)o*HWSZ, i1 = ob1 + (size_t)o*HWSZ;
            float v0 = a0[tm][r] + bias[o];
            float v1 = a1[tm][r] + bias[o];
            if (OUT_RES) { v0 += res[i0]; v1 += res[i1];
                           ((float*)out_)[i0] = v0; ((float*)out_)[i1] = v1; }
            else         { ((unsigned short*)out_)[i0] = f2bf(v0); ((unsigned short*)out_)[i1] = f2bf(v1); }
            s0 += v0; q0 += v0*v0; s1 += v1; q1 += v1*v1;
        }
    }
    for (int off = 32; off > 0; off >>= 1) {
        s0 += __shfl_down(s0, off); q0 += __shfl_down(q0, off);
        s1 += __shfl_down(s1, off); q1 += __shfl_down(q1, off);
    }
    if (lane == 0) { red[wid] = make_float2(s0, q0); red[4+wid] = make_float2(s1, q1); }
    __syncthreads();
    if (tid == 0) {
        float S0=0,Q0=0,S1=0,Q1=0;
        for (int i = 0; i < 4; i++) { S0 += red[i].x; Q0 += red[i].y; S1 += red[4+i].x; Q1 += red[4+i].y; }
        part[b0*49 + blockIdx.x] = make_float2(S0, Q0);
        part[b1*49 + blockIdx.x] = make_float2(S1, Q1);
    }
}

// ================= depthwise 3x3: fused gelu(gn(t1)) on stage-in, stats epilogue =================
__global__ __launch_bounds__(256) void dw_fused(const unsigned short* __restrict__ t1,
        const float* __restrict__ dww, const float* __restrict__ dwb,
        const float2* __restrict__ st_in, const float* __restrict__ gam, const float* __restrict__ bet,
        unsigned short* __restrict__ t2, float2* __restrict__ part) {
    __shared__ float tile[HH*57];
    __shared__ float2 red[4];
    int bc = blockIdx.x;
    int b = bc / CC, c = bc - b*CC;
    int tid = threadIdx.x;
    float2 st = st_in[b];
    float ga = gam[c]*st.y;
    float bb = __builtin_fmaf(-st.x, ga, bet[c]);
    const unsigned short* ip = t1 + (size_t)bc*HWSZ;
    for (int i = tid; i < HWSZ; i += 256) {
        float v = __builtin_fmaf(bf2f(ip[i]), ga, bb);
        tile[(i/WW)*57 + (i%WW)] = gelu_t(v);
    }
    __syncthreads();
    float w00=dww[c*9+0],w01=dww[c*9+1],w02=dww[c*9+2],
          w10=dww[c*9+3],w11=dww[c*9+4],w12=dww[c*9+5],
          w20=dww[c*9+6],w21=dww[c*9+7],w22=dww[c*9+8];
    float bs = dwb[c];
    unsigned short* op = t2 + (size_t)bc*HWSZ;
    float s = 0.f, q = 0.f;
    for (int i = tid; i < HWSZ; i += 256) {
        int h = i/WW, w_ = i - h*WW;
        float acc = bs;
        int up = h > 0, dn = h < HH-1, lf = w_ > 0, rt = w_ < WW-1;
        const float* rm = &tile[(h-1)*57 + w_];
        const float* r0p = &tile[h*57 + w_];
        const float* rp = &tile[(h+1)*57 + w_];
        if (up) { if (lf) acc += rm[-1]*w00; acc += rm[0]*w01; if (rt) acc += rm[1]*w02; }
        if (lf) acc += r0p[-1]*w10;
        acc += r0p[0]*w11;
        if (rt) acc += r0p[1]*w12;
        if (dn) { if (lf) acc += rp[-1]*w20; acc += rp[0]*w21; if (rt) acc += rp[1]*w22; }
        op[i] = f2bf(acc);
        s += acc; q += acc*acc;
    }
    for (int off = 32; off > 0; off >>= 1) { s += __shfl_down(s, off); q += __shfl_down(q, off); }
    int wid = tid >> 6, lane = tid & 63;
    if (lane == 0) red[wid] = make_float2(s, q);
    __syncthreads();
    if (tid == 0) {
        for (int i = 1; i < 4; i++) { s += red[i].x; q += red[i].y; }
        part[bc] = make_float2(s, q);   // indexed [b*96+c]
    }
}

// ================= merged LIF: one gelu(gn) pass, H-scan + W-scan on LDS plane =================
__global__ __launch_bounds__(64) void lif_hw(const unsigned short* __restrict__ t2,
        unsigned short* __restrict__ xlr, unsigned short* __restrict__ xtd,
        const float2* __restrict__ st_in, const float* __restrict__ gam, const float* __restrict__ bet,
        const float* __restrict__ tau1p, const float* __restrict__ vth1p,
        const float* __restrict__ tau2p, const float* __restrict__ vth2p) {
    __shared__ float tile[HH*57];
    int bc = blockIdx.x;
    int b = bc / CC, c = bc - b*CC;
    int tid = threadIdx.x;
    float2 st = st_in[b];
    float ga = gam[c]*st.y;
    float bb = __builtin_fmaf(-st.x, ga, bet[c]);
    const unsigned short* ip = t2 + (size_t)bc*HWSZ;
    // stage plane with gn+gelu applied once (vec4: 56%4==0 -> no row crossing)
    for (int i = tid; i < HWSZ/4; i += 64) {
        u16x4 v = *reinterpret_cast<const u16x4*>(ip + i*4);
        int h = i / 14;
        int w0 = (i - h*14)*4;
        float* tp = &tile[h*57 + w0];
        #pragma unroll
        for (int j = 0; j < 4; j++)
            tp[j] = gelu_t(__builtin_fmaf(bf2f((unsigned short)v[j]), ga, bb));
    }
    __syncthreads();
    const float tau1 = *tau1p, vth1 = *vth1p;
    // H-scan: lane = column w; coalesced row-step global writes
    if (tid < WW) {
        float u = 0.f, o = 0.f;
        unsigned short* op = xlr + (size_t)bc*HWSZ + tid;
        for (int h = 0; h < HH; h++) {
            float xv = tile[h*57 + tid];
            u = xv + tau1*u*(1.f - o);
            o = (u - vth1 > 0.f) ? 1.f : 0.f;
            op[h*WW] = (o != 0.f) ? (unsigned short)0x3F80 : (unsigned short)0;
        }
    }
    __syncthreads();   // H-scan reads done before W-scan overwrites tile
    const float tau2 = *tau2p, vth2 = *vth2p;
    // W-scan: lane = row h; overwrite tile with spikes (stride 57 -> <=2-way banks)
    if (tid < HH) {
        float u = 0.f, o = 0.f;
        int off = tid*57;
        for (int w_ = 0; w_ < WW; w_++) {
            float xv = tile[off + w_];
            u = xv + tau2*u*(1.f - o);
            o = (u - vth2 > 0.f) ? 1.f : 0.f;
            tile[off + w_] = o;
        }
    }
    __syncthreads();
    unsigned int* op32 = (unsigned int*)(xtd + (size_t)bc*HWSZ);
    for (int i = tid; i < HWSZ/2; i += 64) {
        int h = i / 28;
        int w0 = (i - h*28)*2;
        unsigned int lo = tile[h*57 + w0]     != 0.f ? 0x3F80u : 0u;
        unsigned int hi = tile[h*57 + w0 + 1] != 0.f ? 0x3F80u : 0u;
        op32[i] = lo | (hi << 16);
    }
}

// ================= dual conv: gelu(conv(xlr,w21)) + gelu(conv(xtd,w22)), stats epilogue =================
__global__ __launch_bounds__(256) void dual_mfma(const unsigned short* __restrict__ xa_g, const unsigned short* __restrict__ xb_g,
        const unsigned short* __restrict__ w1bf, const float* __restrict__ b1,
        const unsigned short* __restrict__ w2bf, const float* __restrict__ b2,
        unsigned short* __restrict__ out, float2* __restrict__ part) {
    __shared__ unsigned short xa[64][NP];
    __shared__ unsigned short xb[64][NP];
    __shared__ float2 red[4];
    int tid = threadIdx.x;
    int b = blockIdx.y;
    int hw0 = blockIdx.x * 64;
    int col = tid & 63;
    const unsigned short* ap = xa_g + (size_t)b*CHW + hw0 + col;
    const unsigned short* bp = xb_g + (size_t)b*CHW + hw0 + col;
    for (int c4 = (tid >> 6)*4; c4 < CC; c4 += 16) {
        unsigned int pa0, pa1, pb0, pb1;
        unsigned short a0 = ap[(size_t)(c4+0)*HWSZ], a1v = ap[(size_t)(c4+1)*HWSZ];
        unsigned short a2 = ap[(size_t)(c4+2)*HWSZ], a3 = ap[(size_t)(c4+3)*HWSZ];
        unsigned short b0v = bp[(size_t)(c4+0)*HWSZ], b1v = bp[(size_t)(c4+1)*HWSZ];
        unsigned short b2v = bp[(size_t)(c4+2)*HWSZ], b3v = bp[(size_t)(c4+3)*HWSZ];
        pa0 = (unsigned int)a0 | ((unsigned int)a1v << 16);
        pa1 = (unsigned int)a2 | ((unsigned int)a3 << 16);
        pb0 = (unsigned int)b0v | ((unsigned int)b1v << 16);
        pb1 = (unsigned int)b2v | ((unsigned int)b3v << 16);
        *reinterpret_cast<uint2*>(&xa[col][c4]) = make_uint2(pa0, pa1);
        *reinterpret_cast<uint2*>(&xb[col][c4]) = make_uint2(pb0, pb1);
    }
    __syncthreads();
    int lane = tid & 63, wid = tid >> 6;
    int ln = lane & 15, k0 = (lane >> 4)*8, n0 = wid*16;
    const unsigned short* wl1 = w1bf + lane*8;
    const unsigned short* wl2 = w2bf + lane*8;
    f32x4 acc1[6], acc2[6];
    #pragma unroll
    for (int t = 0; t < 6; t++) { acc1[t] = (f32x4){0,0,0,0}; acc2[t] = (f32x4){0,0,0,0}; }
    #pragma unroll
    for (int ks = 0; ks < 3; ks++) {
        bf16x8 bfa = ldfrag(&xa[n0+ln][ks*32+k0]);
        bf16x8 bfb = ldfrag(&xb[n0+ln][ks*32+k0]);
        #pragma unroll
        for (int tm = 0; tm < 6; tm++) {
            bf16x8 af1 = ldfrag(wl1 + (tm*3+ks)*512);
            bf16x8 af2 = ldfrag(wl2 + (tm*3+ks)*512);
            acc1[tm] = __builtin_amdgcn_mfma_f32_16x16x32_bf16(af1, bfa, acc1[tm], 0, 0, 0);
            acc2[tm] = __builtin_amdgcn_mfma_f32_16x16x32_bf16(af2, bfb, acc2[tm], 0, 0, 0);
        }
    }
    int r0i = (lane >> 4)*4;
    size_t ob = (size_t)b*CHW + hw0 + n0 + ln;
    float s = 0.f, q = 0.f;
    #pragma unroll
    for (int tm = 0; tm < 6; tm++) {
        #pragma unroll
        for (int r = 0; r < 4; r++) {
            int o = tm*16 + r0i + r;
            float v = gelu_t(acc1[tm][r] + b1[o]) + gelu_t(acc2[tm][r] + b2[o]);
            out[ob + (size_t)o*HWSZ] = f2bf(v);
            s += v; q += v*v;
        }
    }
    for (int off = 32; off > 0; off >>= 1) { s += __shfl_down(s, off); q += __shfl_down(q, off); }
    if (lane == 0) red[wid] = make_float2(s, q);
    __syncthreads();
    if (tid == 0) {
        for (int i = 1; i < 4; i++) { s += red[i].x; q += red[i].y; }
        part[b*49 + blockIdx.x] = make_float2(s, q);
    }
}

// ================= fused MLP, 512 threads, M-split: wave = (M-half, col-group) =================
// Wave (mh, cg): output rows [mh*48, mh*48+48), cols cg*32..cg*32+31 of the 128 staged.
// Halves weight-frag loads per MFMA (0.5:1); 4 waves per M-half share identical frags (L1 reuse).
__global__ __launch_bounds__(512, 4) void mlp_mfma(float* __restrict__ xio, const float2* __restrict__ st_in,
        const float* __restrict__ gam, const float* __restrict__ bet,
        const unsigned short* __restrict__ wbf, const float* __restrict__ b1, const float* __restrict__ b2) {
    __shared__ unsigned short xs[128][NP];
    __shared__ unsigned short mc[128][NP];
    __shared__ float gml[CC], btl[CC];
    int tid = threadIdx.x;
    int b0 = blockIdx.y, b1i = b0 + 32;
    int hw0 = blockIdx.x * 64;
    if (tid < CC) { gml[tid] = gam[tid]; btl[tid] = bet[tid]; }
    float2 st0 = st_in[b0], st1 = st_in[b1i];
    __syncthreads();
    {
        int col = tid & 63;
        int bsel0 = (tid >> 6) & 1;
        float2 st = bsel0 ? st1 : st0;
        size_t base = (size_t)(bsel0 ? b1i : b0)*CHW + hw0 + col;
        for (int c4 = (tid >> 7)*4; c4 < CC; c4 += 16) {
            unsigned int pk[2];
            #pragma unroll
            for (int j = 0; j < 4; j++) {
                int c = c4 + j;
                float rv = xio[base + (size_t)c*HWSZ];
                float a = st.y * gml[c];
                float bc = __builtin_fmaf(-st.x, a, btl[c]);
                unsigned short h = f2bf(__builtin_fmaf(rv, a, bc));
                if (j < 2) { if (j == 0) pk[0] = h; else pk[0] |= (unsigned int)h << 16; }
                else       { if (j == 2) pk[1] = h; else pk[1] |= (unsigned int)h << 16; }
            }
            *reinterpret_cast<uint2*>(&xs[bsel0*64 + col][c4]) = make_uint2(pk[0], pk[1]);
        }
    }
    __syncthreads();                   // xs fully staged
    int lane = tid & 63, wv = tid >> 6;
    int mh = wv >> 2;                 // M-half: rows mh*48..mh*48+47
    int cg = wv & 3;                  // col-group: staged cols cg*32..cg*32+31
    int ln = lane & 15, k0 = (lane >> 4)*8;
    int r0i = (lane >> 4)*4;
    int xrow0 = cg*32 + ln;
    int xrow1 = xrow0 + 16;
    f32x4 ao[3][2];
    #pragma unroll
    for (int t = 0; t < 3; t++) { ao[t][0] = (f32x4){0,0,0,0}; ao[t][1] = (f32x4){0,0,0,0}; }
    for (int ch = 0; ch < 4; ch++) {
        const unsigned short* w1l = wbf + (4+ch)*9216 + mh*4608 + lane*8;
        const unsigned short* w2l = wbf + (8+ch)*9216 + mh*4608 + lane*8;
        f32x4 c1[3][2];
        #pragma unroll
        for (int t = 0; t < 3; t++) { c1[t][0] = (f32x4){0,0,0,0}; c1[t][1] = (f32x4){0,0,0,0}; }
        __builtin_amdgcn_s_setprio(1);
        #pragma unroll
        for (int ks = 0; ks < 3; ks++) {
            bf16x8 bfa = ldfrag(&xs[xrow0][ks*32+k0]);
            bf16x8 bfb = ldfrag(&xs[xrow1][ks*32+k0]);
            #pragma unroll
            for (int tm = 0; tm < 3; tm++) {
                bf16x8 af = ldfrag(w1l + (tm*3+ks)*512);
                c1[tm][0] = __builtin_amdgcn_mfma_f32_16x16x32_bf16(af, bfa, c1[tm][0], 0, 0, 0);
                c1[tm][1] = __builtin_amdgcn_mfma_f32_16x16x32_bf16(af, bfb, c1[tm][1], 0, 0, 0);
            }
        }
        __builtin_amdgcn_s_setprio(0);
        #pragma unroll
        for (int tm = 0; tm < 3; tm++) {
            int d0 = mh*48 + tm*16 + r0i;
            int dch = ch*CC + d0;
            unsigned short m0 = f2bf(gelu_t(c1[tm][0][0] + b1[dch+0]));
            unsigned short m1 = f2bf(gelu_t(c1[tm][0][1] + b1[dch+1]));
            unsigned short m2 = f2bf(gelu_t(c1[tm][0][2] + b1[dch+2]));
            unsigned short m3 = f2bf(gelu_t(c1[tm][0][3] + b1[dch+3]));
            *reinterpret_cast<uint2*>(&mc[xrow0][d0]) =
                make_uint2((unsigned int)m0 | ((unsigned int)m1 << 16),
                           (unsigned int)m2 | ((unsigned int)m3 << 16));
            unsigned short n0v = f2bf(gelu_t(c1[tm][1][0] + b1[dch+0]));
            unsigned short n1v = f2bf(gelu_t(c1[tm][1][1] + b1[dch+1]));
            unsigned short n2v = f2bf(gelu_t(c1[tm][1][2] + b1[dch+2]));
            unsigned short n3v = f2bf(gelu_t(c1[tm][1][3] + b1[dch+3]));
            *reinterpret_cast<uint2*>(&mc[xrow1][d0]) =
                make_uint2((unsigned int)n0v | ((unsigned int)n1v << 16),
                           (unsigned int)n2v | ((unsigned int)n3v << 16));
        }
        __syncthreads();               // mc complete (both M-halves)
        __builtin_amdgcn_s_setprio(1);
        #pragma unroll
        for (int ks = 0; ks < 3; ks++) {
            bf16x8 bfa = ldfrag(&mc[xrow0][ks*32+k0]);
            bf16x8 bfb = ldfrag(&mc[xrow1][ks*32+k0]);
            #pragma unroll
            for (int tm = 0; tm < 3; tm++) {
                bf16x8 af = ldfrag(w2l + (tm*3+ks)*512);
                ao[tm][0] = __builtin_amdgcn_mfma_f32_16x16x32_bf16(af, bfa, ao[tm][0], 0, 0, 0);
                ao[tm][1] = __builtin_amdgcn_mfma_f32_16x16x32_bf16(af, bfb, ao[tm][1], 0, 0, 0);
            }
        }
        __builtin_amdgcn_s_setprio(0);
        __syncthreads();               // GEMM2 reads done before next chunk overwrites mc
    }
    int bsel = cg >> 1;
    size_t ob = (size_t)(bsel ? b1i : b0)*CHW + hw0 + (cg & 1)*32 + ln;
    #pragma unroll
    for (int tm = 0; tm < 3; tm++) {
        #pragma unroll
        for (int r = 0; r < 4; r++) {
            int o = mh*48 + tm*16 + r0i + r;
            size_t i0 = ob + (size_t)o*HWSZ;
            float bo = b2[o];
            xio[i0]      = xio[i0]      + bo + ao[tm][0][r];
            xio[i0 + 16] = xio[i0 + 16] + bo + ao[tm][1][r];
        }
    }
}

extern "C" void kernel_launch(void* const* d_in, const int* in_sizes, int n_in,
                              void* d_out, int out_size, void* d_ws, size_t ws_size,
                              hipStream_t stream) {
    (void)in_sizes; (void)n_in; (void)out_size; (void)ws_size;
    const float* x    = (const float*)d_in[0];
    const float* n1g  = (const float*)d_in[1];
    const float* n1b  = (const float*)d_in[2];
    const float* c1w  = (const float*)d_in[3];
    const float* c1b  = (const float*)d_in[4];
    const float* g1g  = (const float*)d_in[5];
    const float* g1b  = (const float*)d_in[6];
    const float* dww  = (const float*)d_in[7];
    const float* dwb  = (const float*)d_in[8];
    const float* g2g  = (const float*)d_in[9];
    const float* g2b  = (const float*)d_in[10];
    const float* tau1 = (const float*)d_in[11];
    const float* vth1 = (const float*)d_in[12];
    const float* tau2 = (const float*)d_in[13];
    const float* vth2 = (const float*)d_in[14];
    const float* c21w = (const float*)d_in[15];
    const float* c21b = (const float*)d_in[16];
    const float* c22w = (const float*)d_in[17];
    const float* c22b = (const float*)d_in[18];
    const float* g3g  = (const float*)d_in[19];
    const float* g3b  = (const float*)d_in[20];
    const float* c3w  = (const float*)d_in[21];
    const float* c3b  = (const float*)d_in[22];
    const float* n2g  = (const float*)d_in[23];
    const float* n2b  = (const float*)d_in[24];
    const float* f1w  = (const float*)d_in[25];
    const float* f1b  = (const float*)d_in[26];
    const float* f2w  = (const float*)d_in[27];
    const float* f2b  = (const float*)d_in[28];
    float* out = (float*)d_out;

    unsigned short* A   = (unsigned short*)d_ws;     // 3 bf16 NTOT buffers
    unsigned short* Bb  = A  + NTOT;
    unsigned short* Cc  = Bb + NTOT;
    unsigned short* WBF = Cc + NTOT;                 // 110592 bf16 weights (fragment-repacked)
    float2* part  = (float2*)(WBF + 110592);
    float2* stats = part + 64*96;
    float2* s_n1 = stats, * s_g1 = stats+64, * s_g2 = stats+128, * s_g3 = stats+192, * s_n2 = stats+256;

    const unsigned short* Wc1  = WBF;
    const unsigned short* Wc21 = WBF + 9216;
    const unsigned short* Wc22 = WBF + 18432;
    const unsigned short* Wc3  = WBF + 27648;

    dim3 gStat(S_SPLIT, BB);
    dim3 gPair(HWSZ/64, BB/2);      // (49, 32)
    dim3 gSing(HWSZ/64, BB);        // (49, 64)

    wconv<<<432,256,0,stream>>>(c1w, c21w, c22w, c3w, f1w, f2w, WBF);
    gn_partial<<<gStat,256,0,stream>>>(x, part);
    gn_final<S_SPLIT><<<1,64,0,stream>>>(part, s_n1);
    convk<false,false><<<gPair,256,0,stream>>>(x, Wc1, c1b, s_n1, n1g, n1b, nullptr, A, part);   // t1 -> A (bf16)
    gn_final<49><<<1,64,0,stream>>>(part, s_g1);
    dw_fused<<<BB*CC,256,0,stream>>>(A, dww, dwb, s_g1, g1g, g1b, Bb, part);                     // t2 -> B
    gn_final<CC><<<1,64,0,stream>>>(part, s_g2);
    lif_hw<<<BB*CC,64,0,stream>>>(Bb, A, Cc, s_g2, g2g, g2b, tau1, vth1, tau2, vth2);            // x_lr -> A, x_td -> C
    dual_mfma<<<gSing,256,0,stream>>>(A, Cc, Wc21, c21b, Wc22, c22b, Bb, part);                  // h3 -> B
    gn_final<49><<<1,64,0,stream>>>(part, s_g3);
    convk<true,true><<<gPair,256,0,stream>>>(Bb, Wc3, c3b, s_g3, g3g, g3b, x, out, part);        // x2 -> d_out (f32)
    gn_final<49><<<1,64,0,stream>>>(part, s_n2);
    mlp_mfma<<<gPair,512,0,stream>>>(out, s_n2, n2g, n2b, WBF, f1b, f2b);                        // out = x2 + mlp
}